// Round 12
// baseline (347.965 us; speedup 1.0000x reference)
//
#include <hip/hip_runtime.h>
#include <hip/hip_bf16.h>
#include <cstdio>

#define NB 2
#define NN 4096
#define NC 64
#define NQ 16
#define POS_COEF 0.1f

// ---- workspace layout (float offsets) ----
#define OFF_QT   0u            // [B][N][16] row-major q
#define OFF_QK   131072u       // [B][16][N] planar k-major q (coalesced stream)
#define OFF_XYZ4 262144u       // [B][N][4]  row-major xyz+sq
#define OFF_XYZK 294912u       // [B][4][N]  planar xyz+sq
#define OFF_IRS1 327680u       // [B][N]
#define OFF_IRS2 335872u       // [B][N]
#define OFF_THR  344064u       // [B][N]
#define OFF_ICS1 352256u       // [B][N]  1/(1e-9+cs1)
#define OFF_FLAG 360448u       // [16]
#define OFF_XVB  360464u       // [B][64][N] bf16 (262144 floats)
// --- zeroed region below ---
#define OFF_SUMS 622608u       // [B][4]
#define OFF_GN   622616u       // [2][B][8]
#define OFF_CS2  622648u       // [B][N] colsum of local (k7 by-product)
#define OFF_GMA  630840u       // [B][N][64]  G1 -> res in k8
#define OFF_G2   1155128u      // [B][N][64]  G2 (unnormalized local part)
#define WS_TOTAL 1679416u
#define ZERO_F   (WS_TOTAL - OFF_SUMS)

using bf16x8 = __attribute__((ext_vector_type(8))) short;
using f32x4v = __attribute__((ext_vector_type(4))) float;

__device__ __forceinline__ float rcpf_(float x) { return __builtin_amdgcn_rcpf(x); }
__device__ __forceinline__ unsigned short f2bf(float x) {
  __hip_bfloat16 h = __float2bfloat16(x);
  return *(unsigned short*)&h;
}

__device__ __forceinline__ float ldin(const void* p, size_t i, bool f32) {
  return f32 ? ((const float*)p)[i]
             : __bfloat162float(((const __hip_bfloat16*)p)[i]);
}

// 16-term fma tree, named float4 row against named float4 row
#define DOT16M(A0,A1,A2,A3,B0,B1,B2,B3) \
  fmaf((A0).x,(B0).x, fmaf((A0).y,(B0).y, fmaf((A0).z,(B0).z, fmaf((A0).w,(B0).w, \
  fmaf((A1).x,(B1).x, fmaf((A1).y,(B1).y, fmaf((A1).z,(B1).z, fmaf((A1).w,(B1).w, \
  fmaf((A2).x,(B2).x, fmaf((A2).y,(B2).y, fmaf((A2).z,(B2).z, fmaf((A2).w,(B2).w, \
  fmaf((A3).x,(B3).x, fmaf((A3).y,(B3).y, fmaf((A3).z,(B3).z, (A3).w*(B3).w)))))))))))))))

// dot of named row (M0..M3) against column C of k-planes k0..k15
#define DOTC(M0,M1,M2,M3,C) \
  fmaf((M0).x,k0.C, fmaf((M0).y,k1.C, fmaf((M0).z,k2.C, fmaf((M0).w,k3.C, \
  fmaf((M1).x,k4.C, fmaf((M1).y,k5.C, fmaf((M1).z,k6.C, fmaf((M1).w,k7.C, \
  fmaf((M2).x,k8.C, fmaf((M2).y,k9.C, fmaf((M2).z,k10.C, fmaf((M2).w,k11.C, \
  fmaf((M3).x,k12.C, fmaf((M3).y,k13.C, fmaf((M3).z,k14.C, (M3).w*k15.C)))))))))))))))

// planar k-plane loads: lanes read consecutive float4 -> fully coalesced
#define LKPL(base, n0) \
  const float4 k0  = *(const float4*)((base) + 0*NN  + (n0)); \
  const float4 k1  = *(const float4*)((base) + 1*NN  + (n0)); \
  const float4 k2  = *(const float4*)((base) + 2*NN  + (n0)); \
  const float4 k3  = *(const float4*)((base) + 3*NN  + (n0)); \
  const float4 k4  = *(const float4*)((base) + 4*NN  + (n0)); \
  const float4 k5  = *(const float4*)((base) + 5*NN  + (n0)); \
  const float4 k6  = *(const float4*)((base) + 6*NN  + (n0)); \
  const float4 k7  = *(const float4*)((base) + 7*NN  + (n0)); \
  const float4 k8  = *(const float4*)((base) + 8*NN  + (n0)); \
  const float4 k9  = *(const float4*)((base) + 9*NN  + (n0)); \
  const float4 k10 = *(const float4*)((base) + 10*NN + (n0)); \
  const float4 k11 = *(const float4*)((base) + 11*NN + (n0)); \
  const float4 k12 = *(const float4*)((base) + 12*NN + (n0)); \
  const float4 k13 = *(const float4*)((base) + 13*NN + (n0)); \
  const float4 k14 = *(const float4*)((base) + 14*NN + (n0)); \
  const float4 k15 = *(const float4*)((base) + 15*NN + (n0));

#define WRED(s) { s += __shfl_xor(s, 32); s += __shfl_xor(s, 16); \
  s += __shfl_xor(s, 8); s += __shfl_xor(s, 4); s += __shfl_xor(s, 2); s += __shfl_xor(s, 1); }

#define LQROW(v, base) \
  const float4 v##0 = *(const float4*)((base)); \
  const float4 v##1 = *(const float4*)((base) + 4); \
  const float4 v##2 = *(const float4*)((base) + 8); \
  const float4 v##3 = *(const float4*)((base) + 12);

// K0: detect input dtype
__global__ __launch_bounds__(256) void k0_detect(
    const unsigned short* __restrict__ ctx_u16, float* __restrict__ flag) {
  const int tid = threadIdx.x;
  int bad = 0;
  for (int i = tid; i < 8192; i += 256) {
    const unsigned short u = ctx_u16[i];
    const int e = (u >> 7) & 0xFF;
    if (e >= 134 || (e >= 1 && e <= 100)) bad++;
  }
  __shared__ int cnt;
  if (tid == 0) cnt = 0;
  __syncthreads();
  atomicAdd(&cnt, bad);
  __syncthreads();
  if (tid == 0) flag[0] = (cnt > 256) ? 1.0f : 0.0f;
}

// K1: q = Wqk @ ctx (row-major + planar), xyz (row + planar), batch sums
__global__ __launch_bounds__(256) void k1_q_xyz(
    const void* __restrict__ ctx, const void* __restrict__ xyz,
    const void* __restrict__ wqk, const float* __restrict__ flag,
    float* __restrict__ qt, float* __restrict__ qk,
    float* __restrict__ xyz4, float* __restrict__ xyzk,
    float* __restrict__ sums) {
  const bool f32 = flag[0] > 0.5f;
  const int tid = threadIdx.x;
  const int b = blockIdx.x >> 4;
  const int n = ((blockIdx.x & 15) << 8) + tid;
  __shared__ float wqT[NQ * NC];  // [c][o]
  for (int i = tid; i < NQ * NC; i += 256) {
    int o = i & 15, c = i >> 4;
    wqT[c * 16 + o] = ldin(wqk, o * 64 + c, f32);
  }
  __syncthreads();
  float4 a0 = {0,0,0,0}, a1 = {0,0,0,0}, a2 = {0,0,0,0}, a3 = {0,0,0,0};
  const size_t cbase = (size_t)b * 64 * NN + n;
#pragma unroll 4
  for (int c = 0; c < 64; ++c) {
    float x = ldin(ctx, cbase + (size_t)c * NN, f32);
    const float4 w0 = *(const float4*)(wqT + c * 16 + 0);
    const float4 w1 = *(const float4*)(wqT + c * 16 + 4);
    const float4 w2 = *(const float4*)(wqT + c * 16 + 8);
    const float4 w3 = *(const float4*)(wqT + c * 16 + 12);
    a0.x = fmaf(w0.x, x, a0.x); a0.y = fmaf(w0.y, x, a0.y); a0.z = fmaf(w0.z, x, a0.z); a0.w = fmaf(w0.w, x, a0.w);
    a1.x = fmaf(w1.x, x, a1.x); a1.y = fmaf(w1.y, x, a1.y); a1.z = fmaf(w1.z, x, a1.z); a1.w = fmaf(w1.w, x, a1.w);
    a2.x = fmaf(w2.x, x, a2.x); a2.y = fmaf(w2.y, x, a2.y); a2.z = fmaf(w2.z, x, a2.z); a2.w = fmaf(w2.w, x, a2.w);
    a3.x = fmaf(w3.x, x, a3.x); a3.y = fmaf(w3.y, x, a3.y); a3.z = fmaf(w3.z, x, a3.z); a3.w = fmaf(w3.w, x, a3.w);
  }
  float* qp = qt + (size_t)(b * NN + n) * 16;
  *(float4*)(qp + 0) = a0; *(float4*)(qp + 4) = a1;
  *(float4*)(qp + 8) = a2; *(float4*)(qp + 12) = a3;
  float* kq = qk + (size_t)b * 16 * NN + n;
  kq[0*NN]=a0.x;  kq[1*NN]=a0.y;  kq[2*NN]=a0.z;  kq[3*NN]=a0.w;
  kq[4*NN]=a1.x;  kq[5*NN]=a1.y;  kq[6*NN]=a1.z;  kq[7*NN]=a1.w;
  kq[8*NN]=a2.x;  kq[9*NN]=a2.y;  kq[10*NN]=a2.z; kq[11*NN]=a2.w;
  kq[12*NN]=a3.x; kq[13*NN]=a3.y; kq[14*NN]=a3.z; kq[15*NN]=a3.w;
  float xx = ldin(xyz, (size_t)(b * NN + n) * 3 + 0, f32);
  float yy = ldin(xyz, (size_t)(b * NN + n) * 3 + 1, f32);
  float zz = ldin(xyz, (size_t)(b * NN + n) * 3 + 2, f32);
  float4 p; p.x = xx; p.y = yy; p.z = zz; p.w = fmaf(xx, xx, fmaf(yy, yy, zz * zz));
  *(float4*)(xyz4 + (size_t)(b * NN + n) * 4) = p;
  float* kx = xyzk + (size_t)b * 4 * NN + n;
  kx[0*NN]=p.x; kx[1*NN]=p.y; kx[2*NN]=p.z; kx[3*NN]=p.w;
  float sx = p.x, sy = p.y, sz = p.z, sw = p.w;
  WRED(sx) WRED(sy) WRED(sz) WRED(sw)
  if ((tid & 63) == 0) {
    atomicAdd(&sums[b * 4 + 0], sx);
    atomicAdd(&sums[b * 4 + 1], sy);
    atomicAdd(&sums[b * 4 + 2], sz);
    atomicAdd(&sums[b * 4 + 3], sw);
  }
}

// K2: xv = Wv @ motion + bv, bf16 channel-major [b][c][n]
__global__ __launch_bounds__(256) void k2_xv(
    const void* __restrict__ mot, const void* __restrict__ wv,
    const void* __restrict__ bv, const float* __restrict__ flag,
    unsigned short* __restrict__ xvb) {
  const bool f32 = flag[0] > 0.5f;
  const int tid = threadIdx.x;
  const int b = blockIdx.x >> 6;
  const int n = ((blockIdx.x & 63) << 6) + (tid >> 2);
  const int og = tid & 3;
  __shared__ float wvT[NC * NC];
  __shared__ float bvs[NC];
  for (int i = tid; i < NC * NC; i += 256) {
    int o = i & 63, c = i >> 6;
    wvT[c * 64 + o] = ldin(wv, o * 64 + c, f32);
  }
  if (tid < 64) bvs[tid] = ldin(bv, tid, f32);
  __syncthreads();
  float4 a0 = *(const float4*)(bvs + og * 16 + 0);
  float4 a1 = *(const float4*)(bvs + og * 16 + 4);
  float4 a2 = *(const float4*)(bvs + og * 16 + 8);
  float4 a3 = *(const float4*)(bvs + og * 16 + 12);
  const size_t mbase = (size_t)b * 64 * NN + n;
#pragma unroll 4
  for (int c = 0; c < 64; ++c) {
    float x = ldin(mot, mbase + (size_t)c * NN, f32);
    const float4 w0 = *(const float4*)(wvT + c * 64 + og * 16 + 0);
    const float4 w1 = *(const float4*)(wvT + c * 64 + og * 16 + 4);
    const float4 w2 = *(const float4*)(wvT + c * 64 + og * 16 + 8);
    const float4 w3 = *(const float4*)(wvT + c * 64 + og * 16 + 12);
    a0.x = fmaf(w0.x, x, a0.x); a0.y = fmaf(w0.y, x, a0.y); a0.z = fmaf(w0.z, x, a0.z); a0.w = fmaf(w0.w, x, a0.w);
    a1.x = fmaf(w1.x, x, a1.x); a1.y = fmaf(w1.y, x, a1.y); a1.z = fmaf(w1.z, x, a1.z); a1.w = fmaf(w1.w, x, a1.w);
    a2.x = fmaf(w2.x, x, a2.x); a2.y = fmaf(w2.y, x, a2.y); a2.z = fmaf(w2.z, x, a2.z); a2.w = fmaf(w2.w, x, a2.w);
    a3.x = fmaf(w3.x, x, a3.x); a3.y = fmaf(w3.y, x, a3.y); a3.z = fmaf(w3.z, x, a3.z); a3.w = fmaf(w3.w, x, a3.w);
  }
  unsigned short* xb = xvb + (size_t)b * 64 * NN + n;
  const int o0 = og * 16;
  xb[(size_t)(o0 + 0) * NN] = f2bf(a0.x);  xb[(size_t)(o0 + 1) * NN] = f2bf(a0.y);
  xb[(size_t)(o0 + 2) * NN] = f2bf(a0.z);  xb[(size_t)(o0 + 3) * NN] = f2bf(a0.w);
  xb[(size_t)(o0 + 4) * NN] = f2bf(a1.x);  xb[(size_t)(o0 + 5) * NN] = f2bf(a1.y);
  xb[(size_t)(o0 + 6) * NN] = f2bf(a1.z);  xb[(size_t)(o0 + 7) * NN] = f2bf(a1.w);
  xb[(size_t)(o0 + 8) * NN] = f2bf(a2.x);  xb[(size_t)(o0 + 9) * NN] = f2bf(a2.y);
  xb[(size_t)(o0 +10) * NN] = f2bf(a2.z);  xb[(size_t)(o0 +11) * NN] = f2bf(a2.w);
  xb[(size_t)(o0 +12) * NN] = f2bf(a3.x);  xb[(size_t)(o0 +13) * NN] = f2bf(a3.y);
  xb[(size_t)(o0 +14) * NN] = f2bf(a3.z);  xb[(size_t)(o0 +15) * NN] = f2bf(a3.w);
}

// K2b: thr[n] = 0.1*(1e-9 + csd[n]) analytic
__global__ __launch_bounds__(256) void k2b_thr(
    const float* __restrict__ xyz4, const float* __restrict__ sums,
    float* __restrict__ thr) {
  const int idx = blockIdx.x * 256 + threadIdx.x;
  const int b = idx >> 12;
  const float4 pn = *(const float4*)(xyz4 + (size_t)idx * 4);
  const float Px = sums[b * 4 + 0], Py = sums[b * 4 + 1];
  const float Pz = sums[b * 4 + 2], S1 = sums[b * 4 + 3];
  float csd = fmaf((float)NN, pn.w, S1)
            - 2.f * (pn.x * Px + pn.y * Py + pn.z * Pz);
  thr[idx] = POS_COEF * (1e-9f + csd);
}

// P1: irs1[m] = 1/sum_n exp(corr). Wave owns 4 m-rows (16/block). Grid 512.
__global__ __launch_bounds__(256) void p1_rs1(
    const float* __restrict__ qt, const float* __restrict__ qk,
    float* __restrict__ irs1) {
  const int tid = threadIdx.x;
  const int b = blockIdx.x >> 8;
  const int m0 = (blockIdx.x & 255) << 4;
  const int w = tid >> 6, lane = tid & 63;
  const float* qb = qt + (size_t)b * NN * 16;
  const float* kb = qk + (size_t)b * 16 * NN;
  const int mA = m0 + w, mB = m0 + w + 4, mC = m0 + w + 8, mD = m0 + w + 12;
  LQROW(ma, qb + (size_t)mA * 16)
  LQROW(mb, qb + (size_t)mB * 16)
  LQROW(mc, qb + (size_t)mC * 16)
  LQROW(md, qb + (size_t)mD * 16)
  float sA = 0.f, sB = 0.f, sC = 0.f, sD = 0.f;
  for (int it = 0; it < 16; ++it) {
    const int n0 = (it << 8) + (lane << 2);
    LKPL(kb, n0)
    sA += __expf(fminf(DOTC(ma0,ma1,ma2,ma3,x), 80.f));
    sA += __expf(fminf(DOTC(ma0,ma1,ma2,ma3,y), 80.f));
    sA += __expf(fminf(DOTC(ma0,ma1,ma2,ma3,z), 80.f));
    sA += __expf(fminf(DOTC(ma0,ma1,ma2,ma3,w), 80.f));
    sB += __expf(fminf(DOTC(mb0,mb1,mb2,mb3,x), 80.f));
    sB += __expf(fminf(DOTC(mb0,mb1,mb2,mb3,y), 80.f));
    sB += __expf(fminf(DOTC(mb0,mb1,mb2,mb3,z), 80.f));
    sB += __expf(fminf(DOTC(mb0,mb1,mb2,mb3,w), 80.f));
    sC += __expf(fminf(DOTC(mc0,mc1,mc2,mc3,x), 80.f));
    sC += __expf(fminf(DOTC(mc0,mc1,mc2,mc3,y), 80.f));
    sC += __expf(fminf(DOTC(mc0,mc1,mc2,mc3,z), 80.f));
    sC += __expf(fminf(DOTC(mc0,mc1,mc2,mc3,w), 80.f));
    sD += __expf(fminf(DOTC(md0,md1,md2,md3,x), 80.f));
    sD += __expf(fminf(DOTC(md0,md1,md2,md3,y), 80.f));
    sD += __expf(fminf(DOTC(md0,md1,md2,md3,z), 80.f));
    sD += __expf(fminf(DOTC(md0,md1,md2,md3,w), 80.f));
  }
  WRED(sA) WRED(sB) WRED(sC) WRED(sD)
  if (lane == 0) {
    irs1[b * NN + mA] = rcpf_(sA);
    irs1[b * NN + mB] = rcpf_(sB);
    irs1[b * NN + mC] = rcpf_(sC);
    irs1[b * NN + mD] = rcpf_(sD);
  }
}

// P2: ics1[n] = 1/(1e-9 + sum_m exp(corr)*irs1[m]). 4 n-rows/wave. Grid 512.
__global__ __launch_bounds__(256) void p2_cs1(
    const float* __restrict__ qt, const float* __restrict__ qk,
    const float* __restrict__ irs1, float* __restrict__ ics1) {
  const int tid = threadIdx.x;
  const int b = blockIdx.x >> 8;
  const int n0t = (blockIdx.x & 255) << 4;
  const int w = tid >> 6, lane = tid & 63;
  const float* qb = qt + (size_t)b * NN * 16;
  const float* kb = qk + (size_t)b * 16 * NN;
  const int nA = n0t + w, nB = n0t + w + 4, nC = n0t + w + 8, nD = n0t + w + 12;
  LQROW(na, qb + (size_t)nA * 16)
  LQROW(nb, qb + (size_t)nB * 16)
  LQROW(nc, qb + (size_t)nC * 16)
  LQROW(nd, qb + (size_t)nD * 16)
  float sA = 0.f, sB = 0.f, sC = 0.f, sD = 0.f;
  for (int it = 0; it < 16; ++it) {
    const int m0 = (it << 8) + (lane << 2);
    LKPL(kb, m0)
    const float4 r1 = *(const float4*)(irs1 + b * NN + m0);
    sA = fmaf(__expf(fminf(DOTC(na0,na1,na2,na3,x), 80.f)), r1.x, sA);
    sA = fmaf(__expf(fminf(DOTC(na0,na1,na2,na3,y), 80.f)), r1.y, sA);
    sA = fmaf(__expf(fminf(DOTC(na0,na1,na2,na3,z), 80.f)), r1.z, sA);
    sA = fmaf(__expf(fminf(DOTC(na0,na1,na2,na3,w), 80.f)), r1.w, sA);
    sB = fmaf(__expf(fminf(DOTC(nb0,nb1,nb2,nb3,x), 80.f)), r1.x, sB);
    sB = fmaf(__expf(fminf(DOTC(nb0,nb1,nb2,nb3,y), 80.f)), r1.y, sB);
    sB = fmaf(__expf(fminf(DOTC(nb0,nb1,nb2,nb3,z), 80.f)), r1.z, sB);
    sB = fmaf(__expf(fminf(DOTC(nb0,nb1,nb2,nb3,w), 80.f)), r1.w, sB);
    sC = fmaf(__expf(fminf(DOTC(nc0,nc1,nc2,nc3,x), 80.f)), r1.x, sC);
    sC = fmaf(__expf(fminf(DOTC(nc0,nc1,nc2,nc3,y), 80.f)), r1.y, sC);
    sC = fmaf(__expf(fminf(DOTC(nc0,nc1,nc2,nc3,z), 80.f)), r1.z, sC);
    sC = fmaf(__expf(fminf(DOTC(nc0,nc1,nc2,nc3,w), 80.f)), r1.w, sC);
    sD = fmaf(__expf(fminf(DOTC(nd0,nd1,nd2,nd3,x), 80.f)), r1.x, sD);
    sD = fmaf(__expf(fminf(DOTC(nd0,nd1,nd2,nd3,y), 80.f)), r1.y, sD);
    sD = fmaf(__expf(fminf(DOTC(nd0,nd1,nd2,nd3,z), 80.f)), r1.z, sD);
    sD = fmaf(__expf(fminf(DOTC(nd0,nd1,nd2,nd3,w), 80.f)), r1.w, sD);
  }
  WRED(sA) WRED(sB) WRED(sC) WRED(sD)
  if (lane == 0) {
    ics1[b * NN + nA] = rcpf_(1e-9f + sA);
    ics1[b * NN + nB] = rcpf_(1e-9f + sB);
    ics1[b * NN + nC] = rcpf_(1e-9f + sC);
    ics1[b * NN + nD] = rcpf_(1e-9f + sD);
  }
}

// P3: irs2[m] = 1/sum_n exp(local0). 4 m-rows/wave. Grid 512.
__global__ __launch_bounds__(256) void p3_rs2(
    const float* __restrict__ qt, const float* __restrict__ qk,
    const float* __restrict__ xyz4, const float* __restrict__ xyzk,
    const float* __restrict__ irs1, const float* __restrict__ ics1,
    const float* __restrict__ thr, float* __restrict__ irs2) {
  const int tid = threadIdx.x;
  const int b = blockIdx.x >> 8;
  const int m0 = (blockIdx.x & 255) << 4;
  const int w = tid >> 6, lane = tid & 63;
  const float* qb = qt + (size_t)b * NN * 16;
  const float* kb = qk + (size_t)b * 16 * NN;
  const float* xk = xyzk + (size_t)b * 4 * NN;
  const int mA = m0 + w, mB = m0 + w + 4, mC = m0 + w + 8, mD = m0 + w + 12;
  LQROW(ma, qb + (size_t)mA * 16)
  LQROW(mb, qb + (size_t)mB * 16)
  LQROW(mc, qb + (size_t)mC * 16)
  LQROW(md, qb + (size_t)mD * 16)
  const float4 pmA = *(const float4*)(xyz4 + ((size_t)b * NN + mA) * 4);
  const float4 pmB = *(const float4*)(xyz4 + ((size_t)b * NN + mB) * 4);
  const float4 pmC = *(const float4*)(xyz4 + ((size_t)b * NN + mC) * 4);
  const float4 pmD = *(const float4*)(xyz4 + ((size_t)b * NN + mD) * 4);
  const float rA = irs1[b * NN + mA];
  const float rB = irs1[b * NN + mB];
  const float rC = irs1[b * NN + mC];
  const float rD = irs1[b * NN + mD];
  float sA = 0.f, sB = 0.f, sC = 0.f, sD = 0.f;
#define P3C(S, M0,M1,M2,M3, PM, R, C) { \
    float corr_ = DOTC(M0,M1,M2,M3,C); \
    float a1v_ = __expf(fminf(corr_, 80.f)) * (R) * ic.C; \
    float dd_ = (PM).w + pw.C - 2.f * ((PM).x * px.C + (PM).y * py.C + (PM).z * pz.C); \
    dd_ = fmaxf(dd_, 0.f); \
    float l0_ = (dd_ <= th.C) ? a1v_ : 0.f; \
    S += __expf(l0_); }
  for (int it = 0; it < 16; ++it) {
    const int n0 = (it << 8) + (lane << 2);
    LKPL(kb, n0)
    const float4 px = *(const float4*)(xk + 0*NN + n0);
    const float4 py = *(const float4*)(xk + 1*NN + n0);
    const float4 pz = *(const float4*)(xk + 2*NN + n0);
    const float4 pw = *(const float4*)(xk + 3*NN + n0);
    const float4 ic = *(const float4*)(ics1 + b * NN + n0);
    const float4 th = *(const float4*)(thr + b * NN + n0);
    P3C(sA, ma0,ma1,ma2,ma3, pmA, rA, x)
    P3C(sA, ma0,ma1,ma2,ma3, pmA, rA, y)
    P3C(sA, ma0,ma1,ma2,ma3, pmA, rA, z)
    P3C(sA, ma0,ma1,ma2,ma3, pmA, rA, w)
    P3C(sB, mb0,mb1,mb2,mb3, pmB, rB, x)
    P3C(sB, mb0,mb1,mb2,mb3, pmB, rB, y)
    P3C(sB, mb0,mb1,mb2,mb3, pmB, rB, z)
    P3C(sB, mb0,mb1,mb2,mb3, pmB, rB, w)
    P3C(sC, mc0,mc1,mc2,mc3, pmC, rC, x)
    P3C(sC, mc0,mc1,mc2,mc3, pmC, rC, y)
    P3C(sC, mc0,mc1,mc2,mc3, pmC, rC, z)
    P3C(sC, mc0,mc1,mc2,mc3, pmC, rC, w)
    P3C(sD, md0,md1,md2,md3, pmD, rD, x)
    P3C(sD, md0,md1,md2,md3, pmD, rD, y)
    P3C(sD, md0,md1,md2,md3, pmD, rD, z)
    P3C(sD, md0,md1,md2,md3, pmD, rD, w)
  }
#undef P3C
  WRED(sA) WRED(sB) WRED(sC) WRED(sD)
  if (lane == 0) {
    irs2[b * NN + mA] = rcpf_(sA);
    irs2[b * NN + mB] = rcpf_(sB);
    irs2[b * NN + mC] = rcpf_(sC);
    irs2[b * NN + mD] = rcpf_(sD);
  }
}

// K7: attn tiles (phase A, packed b64 LDS writes) -> dual MFMA vs xv (phase B)
// grid 512 = B * 64 n-tiles * 4 m-split; 16 tiles/block; LDS 27.6 KB
// m-split 4 halves epilogue atomics vs 8 (atomic-RMW drain is the k7 tail)
__global__ __launch_bounds__(256) void k7_gma(
    const float* __restrict__ qt, const float* __restrict__ xyz4,
    const unsigned short* __restrict__ xvb,
    const float* __restrict__ irs1, const float* __restrict__ irs2,
    const float* __restrict__ ics1, const float* __restrict__ thr,
    float* __restrict__ g1, float* __restrict__ g2, float* __restrict__ cs2) {
  const int tid = threadIdx.x;
  const int bid = blockIdx.x;
  const int msl = bid & 3;
  const int nb = (bid >> 2) & 63;
  const int b = bid >> 8;
  const int n0 = nb << 6;
  const int mstart = msl << 10;         // 1024 m per slice
  __shared__ __align__(16) unsigned short attns1[64 * 72];  // [n][m] attn1
  __shared__ __align__(16) unsigned short attns2[64 * 72];  // [n][m] exp(l0)*irs2
  __shared__ __align__(16) unsigned short xvs[64 * 72];     // [c][m]
  const float* qb = qt + (size_t)b * NN * 16;
  const float* pb = xyz4 + (size_t)b * NN * 4;
  const int ni = tid & 63, aw = tid >> 6;
  const int na = n0 + ni;
  const float* qnp = qb + (size_t)na * 16;
  LQROW(q, qnp)
  const float4 pn = *(const float4*)(pb + (size_t)na * 4);
  const float ics1n = ics1[b * NN + na];
  const float thr_n = thr[b * NN + na];
  const int lane = tid & 63, wv = tid >> 6;
  const int lr = lane & 15, quad = lane >> 4;
  const int nw = wv << 4;
  f32x4v acc0 = {0,0,0,0}, acc1 = {0,0,0,0}, acc2 = {0,0,0,0}, acc3 = {0,0,0,0};
  f32x4v d0 = {0,0,0,0}, d1 = {0,0,0,0}, d2 = {0,0,0,0}, d3 = {0,0,0,0};
  float csacc = 0.f;

// compute one attn element (wave-uniform m) into ushort fields D1/D2
#define COMPA(MOFF, D1, D2) { \
    const int m_ = __builtin_amdgcn_readfirstlane(mw + (MOFF)); \
    const float* qm_ = qb + (size_t)m_ * 16; \
    LQROW(wq, qm_) \
    float corr_ = DOT16M(q0, q1, q2, q3, wq0, wq1, wq2, wq3); \
    const float4 pm_ = *(const float4*)(pb + (size_t)m_ * 4); \
    float a1v_ = __expf(fminf(corr_, 80.f)) * irs1[b * NN + m_] * ics1n; \
    float dd_ = pm_.w + pn.w - 2.f * (pm_.x * pn.x + pm_.y * pn.y + pm_.z * pn.z); \
    dd_ = fmaxf(dd_, 0.f); \
    float l0_ = (dd_ <= thr_n) ? a1v_ : 0.f; \
    float l2n_ = __expf(l0_) * irs2[b * NN + m_]; \
    D1 = f2bf(a1v_); D2 = f2bf(l2n_); csacc += l2n_; }

  for (int mt = 0; mt < 16; ++mt) {
    const int m0 = mstart + (mt << 6);
    __syncthreads();
    {
      const int c = tid >> 2, part = tid & 3;
      const unsigned short* src = xvb + ((size_t)b * 64 + c) * NN + m0 + part * 16;
      unsigned short* dst = xvs + c * 72 + part * 16;
      *(uint4*)dst = *(const uint4*)src;
      *(uint4*)(dst + 8) = *(const uint4*)(src + 8);
    }
    // phase A: wave aw owns contiguous m in [m0+16aw, m0+16aw+16);
    // pack 4 m-values into ushort4 -> ds_write_b64
    const int mw = m0 + (aw << 4);
#pragma unroll
    for (int g = 0; g < 4; ++g) {
      ushort4 u1, u2;
      COMPA(g * 4 + 0, u1.x, u2.x)
      COMPA(g * 4 + 1, u1.y, u2.y)
      COMPA(g * 4 + 2, u1.z, u2.z)
      COMPA(g * 4 + 3, u1.w, u2.w)
      *(ushort4*)(attns1 + ni * 72 + (aw << 4) + (g << 2)) = u1;
      *(ushort4*)(attns2 + ni * 72 + (aw << 4) + (g << 2)) = u2;
    }
    __syncthreads();
#pragma unroll
    for (int h = 0; h < 2; ++h) {
      const bf16x8 a1 = *(const bf16x8*)(attns1 + (nw + lr) * 72 + h * 32 + quad * 8);
      const bf16x8 a2 = *(const bf16x8*)(attns2 + (nw + lr) * 72 + h * 32 + quad * 8);
      const bf16x8 b0 = *(const bf16x8*)(xvs + (lr) * 72 + h * 32 + quad * 8);
      const bf16x8 b1 = *(const bf16x8*)(xvs + (16 + lr) * 72 + h * 32 + quad * 8);
      const bf16x8 b2 = *(const bf16x8*)(xvs + (32 + lr) * 72 + h * 32 + quad * 8);
      const bf16x8 b3 = *(const bf16x8*)(xvs + (48 + lr) * 72 + h * 32 + quad * 8);
      acc0 = __builtin_amdgcn_mfma_f32_16x16x32_bf16(a1, b0, acc0, 0, 0, 0);
      acc1 = __builtin_amdgcn_mfma_f32_16x16x32_bf16(a1, b1, acc1, 0, 0, 0);
      acc2 = __builtin_amdgcn_mfma_f32_16x16x32_bf16(a1, b2, acc2, 0, 0, 0);
      acc3 = __builtin_amdgcn_mfma_f32_16x16x32_bf16(a1, b3, acc3, 0, 0, 0);
      d0 = __builtin_amdgcn_mfma_f32_16x16x32_bf16(a2, b0, d0, 0, 0, 0);
      d1 = __builtin_amdgcn_mfma_f32_16x16x32_bf16(a2, b1, d1, 0, 0, 0);
      d2 = __builtin_amdgcn_mfma_f32_16x16x32_bf16(a2, b2, d2, 0, 0, 0);
      d3 = __builtin_amdgcn_mfma_f32_16x16x32_bf16(a2, b3, d3, 0, 0, 0);
    }
  }
#undef COMPA
  atomicAdd(&cs2[b * NN + na], csacc);
#define EPI(ACC, DST, CT) { \
    float* g_ = (DST) + ((size_t)b * NN + n0 + nw + (quad << 2)) * 64 + (CT) * 16 + lr; \
    atomicAdd(g_ + 0,   ACC[0]); \
    atomicAdd(g_ + 64,  ACC[1]); \
    atomicAdd(g_ + 128, ACC[2]); \
    atomicAdd(g_ + 192, ACC[3]); }
  EPI(acc0, g1, 0) EPI(acc1, g1, 1) EPI(acc2, g1, 2) EPI(acc3, g1, 3)
  EPI(d0, g2, 0) EPI(d1, g2, 1) EPI(d2, g2, 2) EPI(d3, g2, 3)
#undef EPI
}

// K8: res = Wt @ (motion - (G1 + G2*ics2)) + bt, in place over G1, + GN partials
__global__ __launch_bounds__(256) void k8_res(
    const void* __restrict__ mot, const void* __restrict__ wt,
    const void* __restrict__ bt, const float* __restrict__ flag,
    float* __restrict__ g1_res, const float* __restrict__ g2,
    const float* __restrict__ cs2, float* __restrict__ gn) {
  const bool f32 = flag[0] > 0.5f;
  const int tid = threadIdx.x;
  const int bid = blockIdx.x;           // 1024 = B * 512
  const int b = bid >> 9;
  const int n0 = (bid & 511) << 3;
  __shared__ float wtT[64 * 65];
  __shared__ float bts[64];
  __shared__ float md[8 * 64];
  __shared__ float gs[8], gss[8];
  for (int i = tid; i < 4096; i += 256) {
    int o = i & 63, c = i >> 6;
    wtT[c * 65 + o] = ldin(wt, o * 64 + c, f32);
  }
  if (tid < 64) bts[tid] = ldin(bt, tid, f32);
  if (tid < 8) { gs[tid] = 0.f; gss[tid] = 0.f; }
#pragma unroll
  for (int r = 0; r < 2; ++r) {
    const int idx = tid * 2 + r;
    const int c = idx & 63, nl = idx >> 6;
    const size_t gi = ((size_t)b * NN + n0 + nl) * 64 + c;
    const float ics2n = rcpf_(1e-9f + cs2[b * NN + n0 + nl]);
    float gmav = fmaf(g2[gi], ics2n, g1_res[gi]);
    md[nl * 64 + c] = ldin(mot, ((size_t)b * 64 + c) * NN + n0 + nl, f32) - gmav;
  }
  __syncthreads();
  const int o = tid & 63, ng = tid >> 6;
  const int nl0 = ng * 2, nl1 = ng * 2 + 1;
  float a0 = bts[o], a1 = bts[o];
#pragma unroll 8
  for (int c = 0; c < 64; ++c) {
    float w = wtT[c * 65 + o];
    a0 = fmaf(w, md[nl0 * 64 + c], a0);
    a1 = fmaf(w, md[nl1 * 64 + c], a1);
  }
  g1_res[((size_t)b * NN + n0 + nl0) * 64 + o] = a0;
  g1_res[((size_t)b * NN + n0 + nl1) * 64 + o] = a1;
  atomicAdd(&gs[o >> 3], a0 + a1);
  atomicAdd(&gss[o >> 3], a0 * a0 + a1 * a1);
  __syncthreads();
  if (tid < 8) atomicAdd(&gn[b * 8 + tid], gs[tid]);
  else if (tid < 16) atomicAdd(&gn[16 + b * 8 + (tid - 8)], gss[tid - 8]);
}

// K9: GroupNorm + PReLU + alpha * gr + motion -> out
__global__ __launch_bounds__(256) void k9_out(
    const float* __restrict__ res, const float* __restrict__ gn,
    const void* __restrict__ mot,
    const void* __restrict__ gnw, const void* __restrict__ gnb,
    const void* __restrict__ pa, const void* __restrict__ al,
    const float* __restrict__ flag, void* __restrict__ out) {
  const bool f32 = flag[0] > 0.5f;
  const int idx = blockIdx.x * 256 + threadIdx.x;
  const int n = idx & 4095;
  const int c = (idx >> 12) & 63;
  const int b = idx >> 18;
  const int g = c >> 3;
  const float inv_cnt = 1.f / 32768.f;
  float mean = gn[b * 8 + g] * inv_cnt;
  float var = gn[16 + b * 8 + g] * inv_cnt - mean * mean;
  var = fmaxf(var, 0.f);
  float rstd = rsqrtf(var + 1e-5f);
  float r = res[((size_t)b * NN + n) * 64 + c];
  float y = (r - mean) * rstd * ldin(gnw, c, f32) + ldin(gnb, c, f32);
  float slope = ldin(pa, 0, f32);
  y = (y >= 0.f) ? y : slope * y;
  float o = ldin(al, 0, f32) * y + ldin(mot, idx, f32);
  if (f32) ((float*)out)[idx] = o;
  else     ((__hip_bfloat16*)out)[idx] = __float2bfloat16(o);
}

extern "C" void kernel_launch(void* const* d_in, const int* in_sizes, int n_in,
                              void* d_out, int out_size, void* d_ws, size_t ws_size,
                              hipStream_t stream) {
  const void* ctx = d_in[0];
  const void* mot = d_in[1];
  const void* xyz = d_in[2];
  const void* wqk = d_in[3];
  const void* wv  = d_in[4];
  const void* bv  = d_in[5];
  const void* wt  = d_in[6];
  const void* bt  = d_in[7];
  const void* gnw = d_in[8];
  const void* gnb = d_in[9];
  const void* pa  = d_in[10];
  const void* al  = d_in[11];
  float* ws = (float*)d_ws;

  if (ws_size < (size_t)WS_TOTAL * sizeof(float))
    fprintf(stderr, "[gma3d] WARNING ws_size=%zu < needed %zu\n",
            ws_size, (size_t)WS_TOTAL * sizeof(float));

  hipMemsetAsync(ws + OFF_SUMS, 0, (size_t)ZERO_F * sizeof(float), stream);

  k0_detect<<<1, 256, 0, stream>>>((const unsigned short*)ctx, ws + OFF_FLAG);
  k1_q_xyz<<<32, 256, 0, stream>>>(ctx, xyz, wqk, ws + OFF_FLAG,
                                   ws + OFF_QT, ws + OFF_QK,
                                   ws + OFF_XYZ4, ws + OFF_XYZK, ws + OFF_SUMS);
  k2_xv<<<128, 256, 0, stream>>>(mot, wv, bv, ws + OFF_FLAG,
                                 (unsigned short*)(ws + OFF_XVB));
  k2b_thr<<<32, 256, 0, stream>>>(ws + OFF_XYZ4, ws + OFF_SUMS, ws + OFF_THR);
  p1_rs1<<<512, 256, 0, stream>>>(ws + OFF_QT, ws + OFF_QK, ws + OFF_IRS1);
  p2_cs1<<<512, 256, 0, stream>>>(ws + OFF_QT, ws + OFF_QK, ws + OFF_IRS1, ws + OFF_ICS1);
  p3_rs2<<<512, 256, 0, stream>>>(ws + OFF_QT, ws + OFF_QK,
                                  ws + OFF_XYZ4, ws + OFF_XYZK,
                                  ws + OFF_IRS1, ws + OFF_ICS1, ws + OFF_THR,
                                  ws + OFF_IRS2);
  k7_gma<<<512, 256, 0, stream>>>(ws + OFF_QT, ws + OFF_XYZ4,
                                  (const unsigned short*)(ws + OFF_XVB),
                                  ws + OFF_IRS1, ws + OFF_IRS2,
                                  ws + OFF_ICS1, ws + OFF_THR,
                                  ws + OFF_GMA, ws + OFF_G2, ws + OFF_CS2);
  k8_res<<<1024, 256, 0, stream>>>(mot, wt, bt, ws + OFF_FLAG,
                                   ws + OFF_GMA, ws + OFF_G2, ws + OFF_CS2, ws + OFF_GN);
  k9_out<<<2048, 256, 0, stream>>>(ws + OFF_GMA, ws + OFF_GN, mot, gnw, gnb, pa, al,
                                   ws + OFF_FLAG, d_out);
}

// Round 13
// 338.370 us; speedup vs baseline: 1.0284x; 1.0284x over previous
//
#include <hip/hip_runtime.h>
#include <hip/hip_bf16.h>
#include <cstdio>

#define NB 2
#define NN 4096
#define NC 64
#define NQ 16
#define POS_COEF 0.1f

// ---- workspace layout (float offsets) ----
#define OFF_QT   0u            // [B][N][16] row-major q
#define OFF_QK   131072u       // [B][16][N] planar k-major q (coalesced stream)
#define OFF_XYZ4 262144u       // [B][N][4]  row-major xyz+sq
#define OFF_XYZK 294912u       // [B][4][N]  planar xyz+sq
#define OFF_IRS1 327680u       // [B][N]
#define OFF_IRS2 335872u       // [B][N]
#define OFF_THR  344064u       // [B][N]
#define OFF_ICS1 352256u       // [B][N]  1/(1e-9+cs1)
#define OFF_FLAG 360448u       // [16]
#define OFF_XVB  360464u       // [B][64][N] bf16 (262144 floats)
// --- zeroed region below ---
#define OFF_SUMS 622608u       // [B][4]
#define OFF_GN   622616u       // [2][B][8]
#define OFF_CS2  622648u       // [B][N] colsum of local (k7 by-product)
#define OFF_GMA  630840u       // [B][N][64]  G1 -> res in k8
#define OFF_G2   1155128u      // [B][N][64]  G2 (unnormalized local part)
#define WS_TOTAL 1679416u
#define ZERO_F   (WS_TOTAL - OFF_SUMS)

using bf16x8 = __attribute__((ext_vector_type(8))) short;
using f32x4v = __attribute__((ext_vector_type(4))) float;

__device__ __forceinline__ float rcpf_(float x) { return __builtin_amdgcn_rcpf(x); }
__device__ __forceinline__ unsigned short f2bf(float x) {
  __hip_bfloat16 h = __float2bfloat16(x);
  return *(unsigned short*)&h;
}

__device__ __forceinline__ float ldin(const void* p, size_t i, bool f32) {
  return f32 ? ((const float*)p)[i]
             : __bfloat162float(((const __hip_bfloat16*)p)[i]);
}

// 16-term fma tree, named float4 row against named float4 row
#define DOT16M(A0,A1,A2,A3,B0,B1,B2,B3) \
  fmaf((A0).x,(B0).x, fmaf((A0).y,(B0).y, fmaf((A0).z,(B0).z, fmaf((A0).w,(B0).w, \
  fmaf((A1).x,(B1).x, fmaf((A1).y,(B1).y, fmaf((A1).z,(B1).z, fmaf((A1).w,(B1).w, \
  fmaf((A2).x,(B2).x, fmaf((A2).y,(B2).y, fmaf((A2).z,(B2).z, fmaf((A2).w,(B2).w, \
  fmaf((A3).x,(B3).x, fmaf((A3).y,(B3).y, fmaf((A3).z,(B3).z, (A3).w*(B3).w)))))))))))))))

// dot of named row (M0..M3) against column C of k-planes k0..k15
#define DOTC(M0,M1,M2,M3,C) \
  fmaf((M0).x,k0.C, fmaf((M0).y,k1.C, fmaf((M0).z,k2.C, fmaf((M0).w,k3.C, \
  fmaf((M1).x,k4.C, fmaf((M1).y,k5.C, fmaf((M1).z,k6.C, fmaf((M1).w,k7.C, \
  fmaf((M2).x,k8.C, fmaf((M2).y,k9.C, fmaf((M2).z,k10.C, fmaf((M2).w,k11.C, \
  fmaf((M3).x,k12.C, fmaf((M3).y,k13.C, fmaf((M3).z,k14.C, (M3).w*k15.C)))))))))))))))

// planar k-plane loads: lanes read consecutive float4 -> fully coalesced
#define LKPL(base, n0) \
  const float4 k0  = *(const float4*)((base) + 0*NN  + (n0)); \
  const float4 k1  = *(const float4*)((base) + 1*NN  + (n0)); \
  const float4 k2  = *(const float4*)((base) + 2*NN  + (n0)); \
  const float4 k3  = *(const float4*)((base) + 3*NN  + (n0)); \
  const float4 k4  = *(const float4*)((base) + 4*NN  + (n0)); \
  const float4 k5  = *(const float4*)((base) + 5*NN  + (n0)); \
  const float4 k6  = *(const float4*)((base) + 6*NN  + (n0)); \
  const float4 k7  = *(const float4*)((base) + 7*NN  + (n0)); \
  const float4 k8  = *(const float4*)((base) + 8*NN  + (n0)); \
  const float4 k9  = *(const float4*)((base) + 9*NN  + (n0)); \
  const float4 k10 = *(const float4*)((base) + 10*NN + (n0)); \
  const float4 k11 = *(const float4*)((base) + 11*NN + (n0)); \
  const float4 k12 = *(const float4*)((base) + 12*NN + (n0)); \
  const float4 k13 = *(const float4*)((base) + 13*NN + (n0)); \
  const float4 k14 = *(const float4*)((base) + 14*NN + (n0)); \
  const float4 k15 = *(const float4*)((base) + 15*NN + (n0));

#define WRED(s) { s += __shfl_xor(s, 32); s += __shfl_xor(s, 16); \
  s += __shfl_xor(s, 8); s += __shfl_xor(s, 4); s += __shfl_xor(s, 2); s += __shfl_xor(s, 1); }

#define LQROW(v, base) \
  const float4 v##0 = *(const float4*)((base)); \
  const float4 v##1 = *(const float4*)((base) + 4); \
  const float4 v##2 = *(const float4*)((base) + 8); \
  const float4 v##3 = *(const float4*)((base) + 12);

// K0: detect input dtype
__global__ __launch_bounds__(256) void k0_detect(
    const unsigned short* __restrict__ ctx_u16, float* __restrict__ flag) {
  const int tid = threadIdx.x;
  int bad = 0;
  for (int i = tid; i < 8192; i += 256) {
    const unsigned short u = ctx_u16[i];
    const int e = (u >> 7) & 0xFF;
    if (e >= 134 || (e >= 1 && e <= 100)) bad++;
  }
  __shared__ int cnt;
  if (tid == 0) cnt = 0;
  __syncthreads();
  atomicAdd(&cnt, bad);
  __syncthreads();
  if (tid == 0) flag[0] = (cnt > 256) ? 1.0f : 0.0f;
}

// K1: q = Wqk @ ctx (row-major + planar), xyz (row + planar), batch sums
__global__ __launch_bounds__(256) void k1_q_xyz(
    const void* __restrict__ ctx, const void* __restrict__ xyz,
    const void* __restrict__ wqk, const float* __restrict__ flag,
    float* __restrict__ qt, float* __restrict__ qk,
    float* __restrict__ xyz4, float* __restrict__ xyzk,
    float* __restrict__ sums) {
  const bool f32 = flag[0] > 0.5f;
  const int tid = threadIdx.x;
  const int b = blockIdx.x >> 4;
  const int n = ((blockIdx.x & 15) << 8) + tid;
  __shared__ float wqT[NQ * NC];  // [c][o]
  for (int i = tid; i < NQ * NC; i += 256) {
    int o = i & 15, c = i >> 4;
    wqT[c * 16 + o] = ldin(wqk, o * 64 + c, f32);
  }
  __syncthreads();
  float4 a0 = {0,0,0,0}, a1 = {0,0,0,0}, a2 = {0,0,0,0}, a3 = {0,0,0,0};
  const size_t cbase = (size_t)b * 64 * NN + n;
#pragma unroll 4
  for (int c = 0; c < 64; ++c) {
    float x = ldin(ctx, cbase + (size_t)c * NN, f32);
    const float4 w0 = *(const float4*)(wqT + c * 16 + 0);
    const float4 w1 = *(const float4*)(wqT + c * 16 + 4);
    const float4 w2 = *(const float4*)(wqT + c * 16 + 8);
    const float4 w3 = *(const float4*)(wqT + c * 16 + 12);
    a0.x = fmaf(w0.x, x, a0.x); a0.y = fmaf(w0.y, x, a0.y); a0.z = fmaf(w0.z, x, a0.z); a0.w = fmaf(w0.w, x, a0.w);
    a1.x = fmaf(w1.x, x, a1.x); a1.y = fmaf(w1.y, x, a1.y); a1.z = fmaf(w1.z, x, a1.z); a1.w = fmaf(w1.w, x, a1.w);
    a2.x = fmaf(w2.x, x, a2.x); a2.y = fmaf(w2.y, x, a2.y); a2.z = fmaf(w2.z, x, a2.z); a2.w = fmaf(w2.w, x, a2.w);
    a3.x = fmaf(w3.x, x, a3.x); a3.y = fmaf(w3.y, x, a3.y); a3.z = fmaf(w3.z, x, a3.z); a3.w = fmaf(w3.w, x, a3.w);
  }
  float* qp = qt + (size_t)(b * NN + n) * 16;
  *(float4*)(qp + 0) = a0; *(float4*)(qp + 4) = a1;
  *(float4*)(qp + 8) = a2; *(float4*)(qp + 12) = a3;
  float* kq = qk + (size_t)b * 16 * NN + n;
  kq[0*NN]=a0.x;  kq[1*NN]=a0.y;  kq[2*NN]=a0.z;  kq[3*NN]=a0.w;
  kq[4*NN]=a1.x;  kq[5*NN]=a1.y;  kq[6*NN]=a1.z;  kq[7*NN]=a1.w;
  kq[8*NN]=a2.x;  kq[9*NN]=a2.y;  kq[10*NN]=a2.z; kq[11*NN]=a2.w;
  kq[12*NN]=a3.x; kq[13*NN]=a3.y; kq[14*NN]=a3.z; kq[15*NN]=a3.w;
  float xx = ldin(xyz, (size_t)(b * NN + n) * 3 + 0, f32);
  float yy = ldin(xyz, (size_t)(b * NN + n) * 3 + 1, f32);
  float zz = ldin(xyz, (size_t)(b * NN + n) * 3 + 2, f32);
  float4 p; p.x = xx; p.y = yy; p.z = zz; p.w = fmaf(xx, xx, fmaf(yy, yy, zz * zz));
  *(float4*)(xyz4 + (size_t)(b * NN + n) * 4) = p;
  float* kx = xyzk + (size_t)b * 4 * NN + n;
  kx[0*NN]=p.x; kx[1*NN]=p.y; kx[2*NN]=p.z; kx[3*NN]=p.w;
  float sx = p.x, sy = p.y, sz = p.z, sw = p.w;
  WRED(sx) WRED(sy) WRED(sz) WRED(sw)
  if ((tid & 63) == 0) {
    atomicAdd(&sums[b * 4 + 0], sx);
    atomicAdd(&sums[b * 4 + 1], sy);
    atomicAdd(&sums[b * 4 + 2], sz);
    atomicAdd(&sums[b * 4 + 3], sw);
  }
}

// K2: xv = Wv @ motion + bv, bf16 channel-major [b][c][n]
__global__ __launch_bounds__(256) void k2_xv(
    const void* __restrict__ mot, const void* __restrict__ wv,
    const void* __restrict__ bv, const float* __restrict__ flag,
    unsigned short* __restrict__ xvb) {
  const bool f32 = flag[0] > 0.5f;
  const int tid = threadIdx.x;
  const int b = blockIdx.x >> 6;
  const int n = ((blockIdx.x & 63) << 6) + (tid >> 2);
  const int og = tid & 3;
  __shared__ float wvT[NC * NC];
  __shared__ float bvs[NC];
  for (int i = tid; i < NC * NC; i += 256) {
    int o = i & 63, c = i >> 6;
    wvT[c * 64 + o] = ldin(wv, o * 64 + c, f32);
  }
  if (tid < 64) bvs[tid] = ldin(bv, tid, f32);
  __syncthreads();
  float4 a0 = *(const float4*)(bvs + og * 16 + 0);
  float4 a1 = *(const float4*)(bvs + og * 16 + 4);
  float4 a2 = *(const float4*)(bvs + og * 16 + 8);
  float4 a3 = *(const float4*)(bvs + og * 16 + 12);
  const size_t mbase = (size_t)b * 64 * NN + n;
#pragma unroll 4
  for (int c = 0; c < 64; ++c) {
    float x = ldin(mot, mbase + (size_t)c * NN, f32);
    const float4 w0 = *(const float4*)(wvT + c * 64 + og * 16 + 0);
    const float4 w1 = *(const float4*)(wvT + c * 64 + og * 16 + 4);
    const float4 w2 = *(const float4*)(wvT + c * 64 + og * 16 + 8);
    const float4 w3 = *(const float4*)(wvT + c * 64 + og * 16 + 12);
    a0.x = fmaf(w0.x, x, a0.x); a0.y = fmaf(w0.y, x, a0.y); a0.z = fmaf(w0.z, x, a0.z); a0.w = fmaf(w0.w, x, a0.w);
    a1.x = fmaf(w1.x, x, a1.x); a1.y = fmaf(w1.y, x, a1.y); a1.z = fmaf(w1.z, x, a1.z); a1.w = fmaf(w1.w, x, a1.w);
    a2.x = fmaf(w2.x, x, a2.x); a2.y = fmaf(w2.y, x, a2.y); a2.z = fmaf(w2.z, x, a2.z); a2.w = fmaf(w2.w, x, a2.w);
    a3.x = fmaf(w3.x, x, a3.x); a3.y = fmaf(w3.y, x, a3.y); a3.z = fmaf(w3.z, x, a3.z); a3.w = fmaf(w3.w, x, a3.w);
  }
  unsigned short* xb = xvb + (size_t)b * 64 * NN + n;
  const int o0 = og * 16;
  xb[(size_t)(o0 + 0) * NN] = f2bf(a0.x);  xb[(size_t)(o0 + 1) * NN] = f2bf(a0.y);
  xb[(size_t)(o0 + 2) * NN] = f2bf(a0.z);  xb[(size_t)(o0 + 3) * NN] = f2bf(a0.w);
  xb[(size_t)(o0 + 4) * NN] = f2bf(a1.x);  xb[(size_t)(o0 + 5) * NN] = f2bf(a1.y);
  xb[(size_t)(o0 + 6) * NN] = f2bf(a1.z);  xb[(size_t)(o0 + 7) * NN] = f2bf(a1.w);
  xb[(size_t)(o0 + 8) * NN] = f2bf(a2.x);  xb[(size_t)(o0 + 9) * NN] = f2bf(a2.y);
  xb[(size_t)(o0 +10) * NN] = f2bf(a2.z);  xb[(size_t)(o0 +11) * NN] = f2bf(a2.w);
  xb[(size_t)(o0 +12) * NN] = f2bf(a3.x);  xb[(size_t)(o0 +13) * NN] = f2bf(a3.y);
  xb[(size_t)(o0 +14) * NN] = f2bf(a3.z);  xb[(size_t)(o0 +15) * NN] = f2bf(a3.w);
}

// K2b: thr[n] = 0.1*(1e-9 + csd[n]) analytic
__global__ __launch_bounds__(256) void k2b_thr(
    const float* __restrict__ xyz4, const float* __restrict__ sums,
    float* __restrict__ thr) {
  const int idx = blockIdx.x * 256 + threadIdx.x;
  const int b = idx >> 12;
  const float4 pn = *(const float4*)(xyz4 + (size_t)idx * 4);
  const float Px = sums[b * 4 + 0], Py = sums[b * 4 + 1];
  const float Pz = sums[b * 4 + 2], S1 = sums[b * 4 + 3];
  float csd = fmaf((float)NN, pn.w, S1)
            - 2.f * (pn.x * Px + pn.y * Py + pn.z * Pz);
  thr[idx] = POS_COEF * (1e-9f + csd);
}

// P1: irs1[m] = 1/sum_n exp(corr). Wave owns 4 m-rows (16/block). Grid 512.
__global__ __launch_bounds__(256) void p1_rs1(
    const float* __restrict__ qt, const float* __restrict__ qk,
    float* __restrict__ irs1) {
  const int tid = threadIdx.x;
  const int b = blockIdx.x >> 8;
  const int m0 = (blockIdx.x & 255) << 4;
  const int w = tid >> 6, lane = tid & 63;
  const float* qb = qt + (size_t)b * NN * 16;
  const float* kb = qk + (size_t)b * 16 * NN;
  const int mA = m0 + w, mB = m0 + w + 4, mC = m0 + w + 8, mD = m0 + w + 12;
  LQROW(ma, qb + (size_t)mA * 16)
  LQROW(mb, qb + (size_t)mB * 16)
  LQROW(mc, qb + (size_t)mC * 16)
  LQROW(md, qb + (size_t)mD * 16)
  float sA = 0.f, sB = 0.f, sC = 0.f, sD = 0.f;
  for (int it = 0; it < 16; ++it) {
    const int n0 = (it << 8) + (lane << 2);
    LKPL(kb, n0)
    sA += __expf(fminf(DOTC(ma0,ma1,ma2,ma3,x), 80.f));
    sA += __expf(fminf(DOTC(ma0,ma1,ma2,ma3,y), 80.f));
    sA += __expf(fminf(DOTC(ma0,ma1,ma2,ma3,z), 80.f));
    sA += __expf(fminf(DOTC(ma0,ma1,ma2,ma3,w), 80.f));
    sB += __expf(fminf(DOTC(mb0,mb1,mb2,mb3,x), 80.f));
    sB += __expf(fminf(DOTC(mb0,mb1,mb2,mb3,y), 80.f));
    sB += __expf(fminf(DOTC(mb0,mb1,mb2,mb3,z), 80.f));
    sB += __expf(fminf(DOTC(mb0,mb1,mb2,mb3,w), 80.f));
    sC += __expf(fminf(DOTC(mc0,mc1,mc2,mc3,x), 80.f));
    sC += __expf(fminf(DOTC(mc0,mc1,mc2,mc3,y), 80.f));
    sC += __expf(fminf(DOTC(mc0,mc1,mc2,mc3,z), 80.f));
    sC += __expf(fminf(DOTC(mc0,mc1,mc2,mc3,w), 80.f));
    sD += __expf(fminf(DOTC(md0,md1,md2,md3,x), 80.f));
    sD += __expf(fminf(DOTC(md0,md1,md2,md3,y), 80.f));
    sD += __expf(fminf(DOTC(md0,md1,md2,md3,z), 80.f));
    sD += __expf(fminf(DOTC(md0,md1,md2,md3,w), 80.f));
  }
  WRED(sA) WRED(sB) WRED(sC) WRED(sD)
  if (lane == 0) {
    irs1[b * NN + mA] = rcpf_(sA);
    irs1[b * NN + mB] = rcpf_(sB);
    irs1[b * NN + mC] = rcpf_(sC);
    irs1[b * NN + mD] = rcpf_(sD);
  }
}

// P2: ics1[n] = 1/(1e-9 + sum_m exp(corr)*irs1[m]). 4 n-rows/wave. Grid 512.
__global__ __launch_bounds__(256) void p2_cs1(
    const float* __restrict__ qt, const float* __restrict__ qk,
    const float* __restrict__ irs1, float* __restrict__ ics1) {
  const int tid = threadIdx.x;
  const int b = blockIdx.x >> 8;
  const int n0t = (blockIdx.x & 255) << 4;
  const int w = tid >> 6, lane = tid & 63;
  const float* qb = qt + (size_t)b * NN * 16;
  const float* kb = qk + (size_t)b * 16 * NN;
  const int nA = n0t + w, nB = n0t + w + 4, nC = n0t + w + 8, nD = n0t + w + 12;
  LQROW(na, qb + (size_t)nA * 16)
  LQROW(nb, qb + (size_t)nB * 16)
  LQROW(nc, qb + (size_t)nC * 16)
  LQROW(nd, qb + (size_t)nD * 16)
  float sA = 0.f, sB = 0.f, sC = 0.f, sD = 0.f;
  for (int it = 0; it < 16; ++it) {
    const int m0 = (it << 8) + (lane << 2);
    LKPL(kb, m0)
    const float4 r1 = *(const float4*)(irs1 + b * NN + m0);
    sA = fmaf(__expf(fminf(DOTC(na0,na1,na2,na3,x), 80.f)), r1.x, sA);
    sA = fmaf(__expf(fminf(DOTC(na0,na1,na2,na3,y), 80.f)), r1.y, sA);
    sA = fmaf(__expf(fminf(DOTC(na0,na1,na2,na3,z), 80.f)), r1.z, sA);
    sA = fmaf(__expf(fminf(DOTC(na0,na1,na2,na3,w), 80.f)), r1.w, sA);
    sB = fmaf(__expf(fminf(DOTC(nb0,nb1,nb2,nb3,x), 80.f)), r1.x, sB);
    sB = fmaf(__expf(fminf(DOTC(nb0,nb1,nb2,nb3,y), 80.f)), r1.y, sB);
    sB = fmaf(__expf(fminf(DOTC(nb0,nb1,nb2,nb3,z), 80.f)), r1.z, sB);
    sB = fmaf(__expf(fminf(DOTC(nb0,nb1,nb2,nb3,w), 80.f)), r1.w, sB);
    sC = fmaf(__expf(fminf(DOTC(nc0,nc1,nc2,nc3,x), 80.f)), r1.x, sC);
    sC = fmaf(__expf(fminf(DOTC(nc0,nc1,nc2,nc3,y), 80.f)), r1.y, sC);
    sC = fmaf(__expf(fminf(DOTC(nc0,nc1,nc2,nc3,z), 80.f)), r1.z, sC);
    sC = fmaf(__expf(fminf(DOTC(nc0,nc1,nc2,nc3,w), 80.f)), r1.w, sC);
    sD = fmaf(__expf(fminf(DOTC(nd0,nd1,nd2,nd3,x), 80.f)), r1.x, sD);
    sD = fmaf(__expf(fminf(DOTC(nd0,nd1,nd2,nd3,y), 80.f)), r1.y, sD);
    sD = fmaf(__expf(fminf(DOTC(nd0,nd1,nd2,nd3,z), 80.f)), r1.z, sD);
    sD = fmaf(__expf(fminf(DOTC(nd0,nd1,nd2,nd3,w), 80.f)), r1.w, sD);
  }
  WRED(sA) WRED(sB) WRED(sC) WRED(sD)
  if (lane == 0) {
    ics1[b * NN + nA] = rcpf_(1e-9f + sA);
    ics1[b * NN + nB] = rcpf_(1e-9f + sB);
    ics1[b * NN + nC] = rcpf_(1e-9f + sC);
    ics1[b * NN + nD] = rcpf_(1e-9f + sD);
  }
}

// P3: irs2[m] = 1/sum_n exp(local0). 4 m-rows/wave. Grid 512.
__global__ __launch_bounds__(256) void p3_rs2(
    const float* __restrict__ qt, const float* __restrict__ qk,
    const float* __restrict__ xyz4, const float* __restrict__ xyzk,
    const float* __restrict__ irs1, const float* __restrict__ ics1,
    const float* __restrict__ thr, float* __restrict__ irs2) {
  const int tid = threadIdx.x;
  const int b = blockIdx.x >> 8;
  const int m0 = (blockIdx.x & 255) << 4;
  const int w = tid >> 6, lane = tid & 63;
  const float* qb = qt + (size_t)b * NN * 16;
  const float* kb = qk + (size_t)b * 16 * NN;
  const float* xk = xyzk + (size_t)b * 4 * NN;
  const int mA = m0 + w, mB = m0 + w + 4, mC = m0 + w + 8, mD = m0 + w + 12;
  LQROW(ma, qb + (size_t)mA * 16)
  LQROW(mb, qb + (size_t)mB * 16)
  LQROW(mc, qb + (size_t)mC * 16)
  LQROW(md, qb + (size_t)mD * 16)
  const float4 pmA = *(const float4*)(xyz4 + ((size_t)b * NN + mA) * 4);
  const float4 pmB = *(const float4*)(xyz4 + ((size_t)b * NN + mB) * 4);
  const float4 pmC = *(const float4*)(xyz4 + ((size_t)b * NN + mC) * 4);
  const float4 pmD = *(const float4*)(xyz4 + ((size_t)b * NN + mD) * 4);
  const float rA = irs1[b * NN + mA];
  const float rB = irs1[b * NN + mB];
  const float rC = irs1[b * NN + mC];
  const float rD = irs1[b * NN + mD];
  float sA = 0.f, sB = 0.f, sC = 0.f, sD = 0.f;
#define P3C(S, M0,M1,M2,M3, PM, R, C) { \
    float corr_ = DOTC(M0,M1,M2,M3,C); \
    float a1v_ = __expf(fminf(corr_, 80.f)) * (R) * ic.C; \
    float dd_ = (PM).w + pw.C - 2.f * ((PM).x * px.C + (PM).y * py.C + (PM).z * pz.C); \
    dd_ = fmaxf(dd_, 0.f); \
    float l0_ = (dd_ <= th.C) ? a1v_ : 0.f; \
    S += __expf(l0_); }
  for (int it = 0; it < 16; ++it) {
    const int n0 = (it << 8) + (lane << 2);
    LKPL(kb, n0)
    const float4 px = *(const float4*)(xk + 0*NN + n0);
    const float4 py = *(const float4*)(xk + 1*NN + n0);
    const float4 pz = *(const float4*)(xk + 2*NN + n0);
    const float4 pw = *(const float4*)(xk + 3*NN + n0);
    const float4 ic = *(const float4*)(ics1 + b * NN + n0);
    const float4 th = *(const float4*)(thr + b * NN + n0);
    P3C(sA, ma0,ma1,ma2,ma3, pmA, rA, x)
    P3C(sA, ma0,ma1,ma2,ma3, pmA, rA, y)
    P3C(sA, ma0,ma1,ma2,ma3, pmA, rA, z)
    P3C(sA, ma0,ma1,ma2,ma3, pmA, rA, w)
    P3C(sB, mb0,mb1,mb2,mb3, pmB, rB, x)
    P3C(sB, mb0,mb1,mb2,mb3, pmB, rB, y)
    P3C(sB, mb0,mb1,mb2,mb3, pmB, rB, z)
    P3C(sB, mb0,mb1,mb2,mb3, pmB, rB, w)
    P3C(sC, mc0,mc1,mc2,mc3, pmC, rC, x)
    P3C(sC, mc0,mc1,mc2,mc3, pmC, rC, y)
    P3C(sC, mc0,mc1,mc2,mc3, pmC, rC, z)
    P3C(sC, mc0,mc1,mc2,mc3, pmC, rC, w)
    P3C(sD, md0,md1,md2,md3, pmD, rD, x)
    P3C(sD, md0,md1,md2,md3, pmD, rD, y)
    P3C(sD, md0,md1,md2,md3, pmD, rD, z)
    P3C(sD, md0,md1,md2,md3, pmD, rD, w)
  }
#undef P3C
  WRED(sA) WRED(sB) WRED(sC) WRED(sD)
  if (lane == 0) {
    irs2[b * NN + mA] = rcpf_(sA);
    irs2[b * NN + mB] = rcpf_(sB);
    irs2[b * NN + mC] = rcpf_(sC);
    irs2[b * NN + mD] = rcpf_(sD);
  }
}

// K7: attn tiles (phase A, packed b64 LDS writes) -> dual MFMA vs xv (phase B)
// grid 1024 = B * 64 n-tiles * 8 m-split (measured optimum); LDS 27.6 KB
__global__ __launch_bounds__(256) void k7_gma(
    const float* __restrict__ qt, const float* __restrict__ xyz4,
    const unsigned short* __restrict__ xvb,
    const float* __restrict__ irs1, const float* __restrict__ irs2,
    const float* __restrict__ ics1, const float* __restrict__ thr,
    float* __restrict__ g1, float* __restrict__ g2, float* __restrict__ cs2) {
  const int tid = threadIdx.x;
  const int bid = blockIdx.x;
  const int msl = bid & 7;
  const int nb = (bid >> 3) & 63;
  const int b = bid >> 9;
  const int n0 = nb << 6;
  const int mstart = msl << 9;          // 512 m per slice
  __shared__ __align__(16) unsigned short attns1[64 * 72];  // [n][m] attn1
  __shared__ __align__(16) unsigned short attns2[64 * 72];  // [n][m] exp(l0)*irs2
  __shared__ __align__(16) unsigned short xvs[64 * 72];     // [c][m]
  const float* qb = qt + (size_t)b * NN * 16;
  const float* pb = xyz4 + (size_t)b * NN * 4;
  const int ni = tid & 63, aw = tid >> 6;
  const int na = n0 + ni;
  const float* qnp = qb + (size_t)na * 16;
  LQROW(q, qnp)
  const float4 pn = *(const float4*)(pb + (size_t)na * 4);
  const float ics1n = ics1[b * NN + na];
  const float thr_n = thr[b * NN + na];
  const int lane = tid & 63, wv = tid >> 6;
  const int lr = lane & 15, quad = lane >> 4;
  const int nw = wv << 4;
  f32x4v acc0 = {0,0,0,0}, acc1 = {0,0,0,0}, acc2 = {0,0,0,0}, acc3 = {0,0,0,0};
  f32x4v d0 = {0,0,0,0}, d1 = {0,0,0,0}, d2 = {0,0,0,0}, d3 = {0,0,0,0};
  float csacc = 0.f;

// compute one attn element (wave-uniform m) into ushort fields D1/D2
#define COMPA(MOFF, D1, D2) { \
    const int m_ = __builtin_amdgcn_readfirstlane(mw + (MOFF)); \
    const float* qm_ = qb + (size_t)m_ * 16; \
    LQROW(wq, qm_) \
    float corr_ = DOT16M(q0, q1, q2, q3, wq0, wq1, wq2, wq3); \
    const float4 pm_ = *(const float4*)(pb + (size_t)m_ * 4); \
    float a1v_ = __expf(fminf(corr_, 80.f)) * irs1[b * NN + m_] * ics1n; \
    float dd_ = pm_.w + pn.w - 2.f * (pm_.x * pn.x + pm_.y * pn.y + pm_.z * pn.z); \
    dd_ = fmaxf(dd_, 0.f); \
    float l0_ = (dd_ <= thr_n) ? a1v_ : 0.f; \
    float l2n_ = __expf(l0_) * irs2[b * NN + m_]; \
    D1 = f2bf(a1v_); D2 = f2bf(l2n_); csacc += l2n_; }

  for (int mt = 0; mt < 8; ++mt) {
    const int m0 = mstart + (mt << 6);
    __syncthreads();
    {
      const int c = tid >> 2, part = tid & 3;
      const unsigned short* src = xvb + ((size_t)b * 64 + c) * NN + m0 + part * 16;
      unsigned short* dst = xvs + c * 72 + part * 16;
      *(uint4*)dst = *(const uint4*)src;
      *(uint4*)(dst + 8) = *(const uint4*)(src + 8);
    }
    // phase A: wave aw owns contiguous m in [m0+16aw, m0+16aw+16);
    // pack 4 m-values into ushort4 -> ds_write_b64
    const int mw = m0 + (aw << 4);
#pragma unroll
    for (int g = 0; g < 4; ++g) {
      ushort4 u1, u2;
      COMPA(g * 4 + 0, u1.x, u2.x)
      COMPA(g * 4 + 1, u1.y, u2.y)
      COMPA(g * 4 + 2, u1.z, u2.z)
      COMPA(g * 4 + 3, u1.w, u2.w)
      *(ushort4*)(attns1 + ni * 72 + (aw << 4) + (g << 2)) = u1;
      *(ushort4*)(attns2 + ni * 72 + (aw << 4) + (g << 2)) = u2;
    }
    __syncthreads();
#pragma unroll
    for (int h = 0; h < 2; ++h) {
      const bf16x8 a1 = *(const bf16x8*)(attns1 + (nw + lr) * 72 + h * 32 + quad * 8);
      const bf16x8 a2 = *(const bf16x8*)(attns2 + (nw + lr) * 72 + h * 32 + quad * 8);
      const bf16x8 b0 = *(const bf16x8*)(xvs + (lr) * 72 + h * 32 + quad * 8);
      const bf16x8 b1 = *(const bf16x8*)(xvs + (16 + lr) * 72 + h * 32 + quad * 8);
      const bf16x8 b2 = *(const bf16x8*)(xvs + (32 + lr) * 72 + h * 32 + quad * 8);
      const bf16x8 b3 = *(const bf16x8*)(xvs + (48 + lr) * 72 + h * 32 + quad * 8);
      acc0 = __builtin_amdgcn_mfma_f32_16x16x32_bf16(a1, b0, acc0, 0, 0, 0);
      acc1 = __builtin_amdgcn_mfma_f32_16x16x32_bf16(a1, b1, acc1, 0, 0, 0);
      acc2 = __builtin_amdgcn_mfma_f32_16x16x32_bf16(a1, b2, acc2, 0, 0, 0);
      acc3 = __builtin_amdgcn_mfma_f32_16x16x32_bf16(a1, b3, acc3, 0, 0, 0);
      d0 = __builtin_amdgcn_mfma_f32_16x16x32_bf16(a2, b0, d0, 0, 0, 0);
      d1 = __builtin_amdgcn_mfma_f32_16x16x32_bf16(a2, b1, d1, 0, 0, 0);
      d2 = __builtin_amdgcn_mfma_f32_16x16x32_bf16(a2, b2, d2, 0, 0, 0);
      d3 = __builtin_amdgcn_mfma_f32_16x16x32_bf16(a2, b3, d3, 0, 0, 0);
    }
  }
#undef COMPA
  atomicAdd(&cs2[b * NN + na], csacc);
#define EPI(ACC, DST, CT) { \
    float* g_ = (DST) + ((size_t)b * NN + n0 + nw + (quad << 2)) * 64 + (CT) * 16 + lr; \
    atomicAdd(g_ + 0,   ACC[0]); \
    atomicAdd(g_ + 64,  ACC[1]); \
    atomicAdd(g_ + 128, ACC[2]); \
    atomicAdd(g_ + 192, ACC[3]); }
  EPI(acc0, g1, 0) EPI(acc1, g1, 1) EPI(acc2, g1, 2) EPI(acc3, g1, 3)
  EPI(d0, g2, 0) EPI(d1, g2, 1) EPI(d2, g2, 2) EPI(d3, g2, 3)
#undef EPI
}

// K8: res = Wt @ (motion - (G1 + G2*ics2)) + bt, in place over G1, + GN partials
__global__ __launch_bounds__(256) void k8_res(
    const void* __restrict__ mot, const void* __restrict__ wt,
    const void* __restrict__ bt, const float* __restrict__ flag,
    float* __restrict__ g1_res, const float* __restrict__ g2,
    const float* __restrict__ cs2, float* __restrict__ gn) {
  const bool f32 = flag[0] > 0.5f;
  const int tid = threadIdx.x;
  const int bid = blockIdx.x;           // 1024 = B * 512
  const int b = bid >> 9;
  const int n0 = (bid & 511) << 3;
  __shared__ float wtT[64 * 65];
  __shared__ float bts[64];
  __shared__ float md[8 * 64];
  __shared__ float gs[8], gss[8];
  for (int i = tid; i < 4096; i += 256) {
    int o = i & 63, c = i >> 6;
    wtT[c * 65 + o] = ldin(wt, o * 64 + c, f32);
  }
  if (tid < 64) bts[tid] = ldin(bt, tid, f32);
  if (tid < 8) { gs[tid] = 0.f; gss[tid] = 0.f; }
#pragma unroll
  for (int r = 0; r < 2; ++r) {
    const int idx = tid * 2 + r;
    const int c = idx & 63, nl = idx >> 6;
    const size_t gi = ((size_t)b * NN + n0 + nl) * 64 + c;
    const float ics2n = rcpf_(1e-9f + cs2[b * NN + n0 + nl]);
    float gmav = fmaf(g2[gi], ics2n, g1_res[gi]);
    md[nl * 64 + c] = ldin(mot, ((size_t)b * 64 + c) * NN + n0 + nl, f32) - gmav;
  }
  __syncthreads();
  const int o = tid & 63, ng = tid >> 6;
  const int nl0 = ng * 2, nl1 = ng * 2 + 1;
  float a0 = bts[o], a1 = bts[o];
#pragma unroll 8
  for (int c = 0; c < 64; ++c) {
    float w = wtT[c * 65 + o];
    a0 = fmaf(w, md[nl0 * 64 + c], a0);
    a1 = fmaf(w, md[nl1 * 64 + c], a1);
  }
  g1_res[((size_t)b * NN + n0 + nl0) * 64 + o] = a0;
  g1_res[((size_t)b * NN + n0 + nl1) * 64 + o] = a1;
  atomicAdd(&gs[o >> 3], a0 + a1);
  atomicAdd(&gss[o >> 3], a0 * a0 + a1 * a1);
  __syncthreads();
  if (tid < 8) atomicAdd(&gn[b * 8 + tid], gs[tid]);
  else if (tid < 16) atomicAdd(&gn[16 + b * 8 + (tid - 8)], gss[tid - 8]);
}

// K9: GroupNorm + PReLU + alpha * gr + motion -> out
__global__ __launch_bounds__(256) void k9_out(
    const float* __restrict__ res, const float* __restrict__ gn,
    const void* __restrict__ mot,
    const void* __restrict__ gnw, const void* __restrict__ gnb,
    const void* __restrict__ pa, const void* __restrict__ al,
    const float* __restrict__ flag, void* __restrict__ out) {
  const bool f32 = flag[0] > 0.5f;
  const int idx = blockIdx.x * 256 + threadIdx.x;
  const int n = idx & 4095;
  const int c = (idx >> 12) & 63;
  const int b = idx >> 18;
  const int g = c >> 3;
  const float inv_cnt = 1.f / 32768.f;
  float mean = gn[b * 8 + g] * inv_cnt;
  float var = gn[16 + b * 8 + g] * inv_cnt - mean * mean;
  var = fmaxf(var, 0.f);
  float rstd = rsqrtf(var + 1e-5f);
  float r = res[((size_t)b * NN + n) * 64 + c];
  float y = (r - mean) * rstd * ldin(gnw, c, f32) + ldin(gnb, c, f32);
  float slope = ldin(pa, 0, f32);
  y = (y >= 0.f) ? y : slope * y;
  float o = ldin(al, 0, f32) * y + ldin(mot, idx, f32);
  if (f32) ((float*)out)[idx] = o;
  else     ((__hip_bfloat16*)out)[idx] = __float2bfloat16(o);
}

extern "C" void kernel_launch(void* const* d_in, const int* in_sizes, int n_in,
                              void* d_out, int out_size, void* d_ws, size_t ws_size,
                              hipStream_t stream) {
  const void* ctx = d_in[0];
  const void* mot = d_in[1];
  const void* xyz = d_in[2];
  const void* wqk = d_in[3];
  const void* wv  = d_in[4];
  const void* bv  = d_in[5];
  const void* wt  = d_in[6];
  const void* bt  = d_in[7];
  const void* gnw = d_in[8];
  const void* gnb = d_in[9];
  const void* pa  = d_in[10];
  const void* al  = d_in[11];
  float* ws = (float*)d_ws;

  if (ws_size < (size_t)WS_TOTAL * sizeof(float))
    fprintf(stderr, "[gma3d] WARNING ws_size=%zu < needed %zu\n",
            ws_size, (size_t)WS_TOTAL * sizeof(float));

  hipMemsetAsync(ws + OFF_SUMS, 0, (size_t)ZERO_F * sizeof(float), stream);

  k0_detect<<<1, 256, 0, stream>>>((const unsigned short*)ctx, ws + OFF_FLAG);
  k1_q_xyz<<<32, 256, 0, stream>>>(ctx, xyz, wqk, ws + OFF_FLAG,
                                   ws + OFF_QT, ws + OFF_QK,
                                   ws + OFF_XYZ4, ws + OFF_XYZK, ws + OFF_SUMS);
  k2_xv<<<128, 256, 0, stream>>>(mot, wv, bv, ws + OFF_FLAG,
                                 (unsigned short*)(ws + OFF_XVB));
  k2b_thr<<<32, 256, 0, stream>>>(ws + OFF_XYZ4, ws + OFF_SUMS, ws + OFF_THR);
  p1_rs1<<<512, 256, 0, stream>>>(ws + OFF_QT, ws + OFF_QK, ws + OFF_IRS1);
  p2_cs1<<<512, 256, 0, stream>>>(ws + OFF_QT, ws + OFF_QK, ws + OFF_IRS1, ws + OFF_ICS1);
  p3_rs2<<<512, 256, 0, stream>>>(ws + OFF_QT, ws + OFF_QK,
                                  ws + OFF_XYZ4, ws + OFF_XYZK,
                                  ws + OFF_IRS1, ws + OFF_ICS1, ws + OFF_THR,
                                  ws + OFF_IRS2);
  k7_gma<<<1024, 256, 0, stream>>>(ws + OFF_QT, ws + OFF_XYZ4,
                                   (const unsigned short*)(ws + OFF_XVB),
                                   ws + OFF_IRS1, ws + OFF_IRS2,
                                   ws + OFF_ICS1, ws + OFF_THR,
                                   ws + OFF_GMA, ws + OFF_G2, ws + OFF_CS2);
  k8_res<<<1024, 256, 0, stream>>>(mot, wt, bt, ws + OFF_FLAG,
                                   ws + OFF_GMA, ws + OFF_G2, ws + OFF_CS2, ws + OFF_GN);
  k9_out<<<2048, 256, 0, stream>>>(ws + OFF_GMA, ws + OFF_GN, mot, gnw, gnb, pa, al,
                                   ws + OFF_FLAG, d_out);
}

// Round 14
// 330.098 us; speedup vs baseline: 1.0541x; 1.0251x over previous
//
#include <hip/hip_runtime.h>
#include <hip/hip_bf16.h>
#include <cstdio>

#define NB 2
#define NN 4096
#define NC 64
#define NQ 16
#define POS_COEF 0.1f

// ---- workspace layout (float offsets) ----
#define OFF_QT   0u            // [B][N][16] row-major q
#define OFF_QK   131072u       // [B][16][N] planar k-major q (coalesced stream)
#define OFF_XYZ4 262144u       // [B][N][4]  row-major xyz+sq
#define OFF_XYZK 294912u       // [B][4][N]  planar xyz+sq
#define OFF_IRS1 327680u       // [B][N]
#define OFF_IRS2 335872u       // [B][N]
#define OFF_THR  344064u       // [B][N]
#define OFF_ICS1 352256u       // [B][N]  1/(1e-9+cs1)
#define OFF_FLAG 360448u       // [16]
#define OFF_XVB  360464u       // [B][64][N] bf16 (262144 floats)
// --- zeroed region below ---
#define OFF_SUMS 622608u       // [B][4]
#define OFF_GN   622616u       // [2][B][8]
#define OFF_CS2  622648u       // [B][N] colsum of local (k7 by-product)
#define OFF_GMA  630840u       // [B][N][64]  G1 -> res in k8
#define OFF_G2   1155128u      // [B][N][64]  G2 (unnormalized local part)
#define WS_TOTAL 1679416u
#define ZERO_F   (WS_TOTAL - OFF_SUMS)
// --- optional materialized exp matrices (bf16), used iff ws_size permits ---
#define OFF_A0   1679424u      // [B][N][N] bf16 exp(corr)     (16777216 floats)
#define OFF_AE   18456640u     // [B][N][N] bf16 exp(l0)       (16777216 floats)
#define FULL_F   35233856u

using bf16x8 = __attribute__((ext_vector_type(8))) short;
using f32x4v = __attribute__((ext_vector_type(4))) float;

__device__ __forceinline__ float rcpf_(float x) { return __builtin_amdgcn_rcpf(x); }
__device__ __forceinline__ unsigned short f2bf(float x) {
  __hip_bfloat16 h = __float2bfloat16(x);
  return *(unsigned short*)&h;
}
__device__ __forceinline__ float bf2f(unsigned short u) {
  unsigned v = ((unsigned)u) << 16;
  return __builtin_bit_cast(float, v);
}

__device__ __forceinline__ float ldin(const void* p, size_t i, bool f32) {
  return f32 ? ((const float*)p)[i]
             : __bfloat162float(((const __hip_bfloat16*)p)[i]);
}

// 16-term fma tree, named float4 row against named float4 row
#define DOT16M(A0,A1,A2,A3,B0,B1,B2,B3) \
  fmaf((A0).x,(B0).x, fmaf((A0).y,(B0).y, fmaf((A0).z,(B0).z, fmaf((A0).w,(B0).w, \
  fmaf((A1).x,(B1).x, fmaf((A1).y,(B1).y, fmaf((A1).z,(B1).z, fmaf((A1).w,(B1).w, \
  fmaf((A2).x,(B2).x, fmaf((A2).y,(B2).y, fmaf((A2).z,(B2).z, fmaf((A2).w,(B2).w, \
  fmaf((A3).x,(B3).x, fmaf((A3).y,(B3).y, fmaf((A3).z,(B3).z, (A3).w*(B3).w)))))))))))))))

// dot of named row (M0..M3) against column C of k-planes k0..k15
#define DOTC(M0,M1,M2,M3,C) \
  fmaf((M0).x,k0.C, fmaf((M0).y,k1.C, fmaf((M0).z,k2.C, fmaf((M0).w,k3.C, \
  fmaf((M1).x,k4.C, fmaf((M1).y,k5.C, fmaf((M1).z,k6.C, fmaf((M1).w,k7.C, \
  fmaf((M2).x,k8.C, fmaf((M2).y,k9.C, fmaf((M2).z,k10.C, fmaf((M2).w,k11.C, \
  fmaf((M3).x,k12.C, fmaf((M3).y,k13.C, fmaf((M3).z,k14.C, (M3).w*k15.C)))))))))))))))

// planar k-plane loads: lanes read consecutive float4 -> fully coalesced
#define LKPL(base, n0) \
  const float4 k0  = *(const float4*)((base) + 0*NN  + (n0)); \
  const float4 k1  = *(const float4*)((base) + 1*NN  + (n0)); \
  const float4 k2  = *(const float4*)((base) + 2*NN  + (n0)); \
  const float4 k3  = *(const float4*)((base) + 3*NN  + (n0)); \
  const float4 k4  = *(const float4*)((base) + 4*NN  + (n0)); \
  const float4 k5  = *(const float4*)((base) + 5*NN  + (n0)); \
  const float4 k6  = *(const float4*)((base) + 6*NN  + (n0)); \
  const float4 k7  = *(const float4*)((base) + 7*NN  + (n0)); \
  const float4 k8  = *(const float4*)((base) + 8*NN  + (n0)); \
  const float4 k9  = *(const float4*)((base) + 9*NN  + (n0)); \
  const float4 k10 = *(const float4*)((base) + 10*NN + (n0)); \
  const float4 k11 = *(const float4*)((base) + 11*NN + (n0)); \
  const float4 k12 = *(const float4*)((base) + 12*NN + (n0)); \
  const float4 k13 = *(const float4*)((base) + 13*NN + (n0)); \
  const float4 k14 = *(const float4*)((base) + 14*NN + (n0)); \
  const float4 k15 = *(const float4*)((base) + 15*NN + (n0));

#define WRED(s) { s += __shfl_xor(s, 32); s += __shfl_xor(s, 16); \
  s += __shfl_xor(s, 8); s += __shfl_xor(s, 4); s += __shfl_xor(s, 2); s += __shfl_xor(s, 1); }

#define LQROW(v, base) \
  const float4 v##0 = *(const float4*)((base)); \
  const float4 v##1 = *(const float4*)((base) + 4); \
  const float4 v##2 = *(const float4*)((base) + 8); \
  const float4 v##3 = *(const float4*)((base) + 12);

// K0: detect input dtype
__global__ __launch_bounds__(256) void k0_detect(
    const unsigned short* __restrict__ ctx_u16, float* __restrict__ flag) {
  const int tid = threadIdx.x;
  int bad = 0;
  for (int i = tid; i < 8192; i += 256) {
    const unsigned short u = ctx_u16[i];
    const int e = (u >> 7) & 0xFF;
    if (e >= 134 || (e >= 1 && e <= 100)) bad++;
  }
  __shared__ int cnt;
  if (tid == 0) cnt = 0;
  __syncthreads();
  atomicAdd(&cnt, bad);
  __syncthreads();
  if (tid == 0) flag[0] = (cnt > 256) ? 1.0f : 0.0f;
}

// K1: q = Wqk @ ctx (row-major + planar), xyz (row + planar), batch sums
__global__ __launch_bounds__(256) void k1_q_xyz(
    const void* __restrict__ ctx, const void* __restrict__ xyz,
    const void* __restrict__ wqk, const float* __restrict__ flag,
    float* __restrict__ qt, float* __restrict__ qk,
    float* __restrict__ xyz4, float* __restrict__ xyzk,
    float* __restrict__ sums) {
  const bool f32 = flag[0] > 0.5f;
  const int tid = threadIdx.x;
  const int b = blockIdx.x >> 4;
  const int n = ((blockIdx.x & 15) << 8) + tid;
  __shared__ float wqT[NQ * NC];  // [c][o]
  for (int i = tid; i < NQ * NC; i += 256) {
    int o = i & 15, c = i >> 4;
    wqT[c * 16 + o] = ldin(wqk, o * 64 + c, f32);
  }
  __syncthreads();
  float4 a0 = {0,0,0,0}, a1 = {0,0,0,0}, a2 = {0,0,0,0}, a3 = {0,0,0,0};
  const size_t cbase = (size_t)b * 64 * NN + n;
#pragma unroll 4
  for (int c = 0; c < 64; ++c) {
    float x = ldin(ctx, cbase + (size_t)c * NN, f32);
    const float4 w0 = *(const float4*)(wqT + c * 16 + 0);
    const float4 w1 = *(const float4*)(wqT + c * 16 + 4);
    const float4 w2 = *(const float4*)(wqT + c * 16 + 8);
    const float4 w3 = *(const float4*)(wqT + c * 16 + 12);
    a0.x = fmaf(w0.x, x, a0.x); a0.y = fmaf(w0.y, x, a0.y); a0.z = fmaf(w0.z, x, a0.z); a0.w = fmaf(w0.w, x, a0.w);
    a1.x = fmaf(w1.x, x, a1.x); a1.y = fmaf(w1.y, x, a1.y); a1.z = fmaf(w1.z, x, a1.z); a1.w = fmaf(w1.w, x, a1.w);
    a2.x = fmaf(w2.x, x, a2.x); a2.y = fmaf(w2.y, x, a2.y); a2.z = fmaf(w2.z, x, a2.z); a2.w = fmaf(w2.w, x, a2.w);
    a3.x = fmaf(w3.x, x, a3.x); a3.y = fmaf(w3.y, x, a3.y); a3.z = fmaf(w3.z, x, a3.z); a3.w = fmaf(w3.w, x, a3.w);
  }
  float* qp = qt + (size_t)(b * NN + n) * 16;
  *(float4*)(qp + 0) = a0; *(float4*)(qp + 4) = a1;
  *(float4*)(qp + 8) = a2; *(float4*)(qp + 12) = a3;
  float* kq = qk + (size_t)b * 16 * NN + n;
  kq[0*NN]=a0.x;  kq[1*NN]=a0.y;  kq[2*NN]=a0.z;  kq[3*NN]=a0.w;
  kq[4*NN]=a1.x;  kq[5*NN]=a1.y;  kq[6*NN]=a1.z;  kq[7*NN]=a1.w;
  kq[8*NN]=a2.x;  kq[9*NN]=a2.y;  kq[10*NN]=a2.z; kq[11*NN]=a2.w;
  kq[12*NN]=a3.x; kq[13*NN]=a3.y; kq[14*NN]=a3.z; kq[15*NN]=a3.w;
  float xx = ldin(xyz, (size_t)(b * NN + n) * 3 + 0, f32);
  float yy = ldin(xyz, (size_t)(b * NN + n) * 3 + 1, f32);
  float zz = ldin(xyz, (size_t)(b * NN + n) * 3 + 2, f32);
  float4 p; p.x = xx; p.y = yy; p.z = zz; p.w = fmaf(xx, xx, fmaf(yy, yy, zz * zz));
  *(float4*)(xyz4 + (size_t)(b * NN + n) * 4) = p;
  float* kx = xyzk + (size_t)b * 4 * NN + n;
  kx[0*NN]=p.x; kx[1*NN]=p.y; kx[2*NN]=p.z; kx[3*NN]=p.w;
  float sx = p.x, sy = p.y, sz = p.z, sw = p.w;
  WRED(sx) WRED(sy) WRED(sz) WRED(sw)
  if ((tid & 63) == 0) {
    atomicAdd(&sums[b * 4 + 0], sx);
    atomicAdd(&sums[b * 4 + 1], sy);
    atomicAdd(&sums[b * 4 + 2], sz);
    atomicAdd(&sums[b * 4 + 3], sw);
  }
}

// K2: xv = Wv @ motion + bv, bf16 channel-major [b][c][n]
__global__ __launch_bounds__(256) void k2_xv(
    const void* __restrict__ mot, const void* __restrict__ wv,
    const void* __restrict__ bv, const float* __restrict__ flag,
    unsigned short* __restrict__ xvb) {
  const bool f32 = flag[0] > 0.5f;
  const int tid = threadIdx.x;
  const int b = blockIdx.x >> 6;
  const int n = ((blockIdx.x & 63) << 6) + (tid >> 2);
  const int og = tid & 3;
  __shared__ float wvT[NC * NC];
  __shared__ float bvs[NC];
  for (int i = tid; i < NC * NC; i += 256) {
    int o = i & 63, c = i >> 6;
    wvT[c * 64 + o] = ldin(wv, o * 64 + c, f32);
  }
  if (tid < 64) bvs[tid] = ldin(bv, tid, f32);
  __syncthreads();
  float4 a0 = *(const float4*)(bvs + og * 16 + 0);
  float4 a1 = *(const float4*)(bvs + og * 16 + 4);
  float4 a2 = *(const float4*)(bvs + og * 16 + 8);
  float4 a3 = *(const float4*)(bvs + og * 16 + 12);
  const size_t mbase = (size_t)b * 64 * NN + n;
#pragma unroll 4
  for (int c = 0; c < 64; ++c) {
    float x = ldin(mot, mbase + (size_t)c * NN, f32);
    const float4 w0 = *(const float4*)(wvT + c * 64 + og * 16 + 0);
    const float4 w1 = *(const float4*)(wvT + c * 64 + og * 16 + 4);
    const float4 w2 = *(const float4*)(wvT + c * 64 + og * 16 + 8);
    const float4 w3 = *(const float4*)(wvT + c * 64 + og * 16 + 12);
    a0.x = fmaf(w0.x, x, a0.x); a0.y = fmaf(w0.y, x, a0.y); a0.z = fmaf(w0.z, x, a0.z); a0.w = fmaf(w0.w, x, a0.w);
    a1.x = fmaf(w1.x, x, a1.x); a1.y = fmaf(w1.y, x, a1.y); a1.z = fmaf(w1.z, x, a1.z); a1.w = fmaf(w1.w, x, a1.w);
    a2.x = fmaf(w2.x, x, a2.x); a2.y = fmaf(w2.y, x, a2.y); a2.z = fmaf(w2.z, x, a2.z); a2.w = fmaf(w2.w, x, a2.w);
    a3.x = fmaf(w3.x, x, a3.x); a3.y = fmaf(w3.y, x, a3.y); a3.z = fmaf(w3.z, x, a3.z); a3.w = fmaf(w3.w, x, a3.w);
  }
  unsigned short* xb = xvb + (size_t)b * 64 * NN + n;
  const int o0 = og * 16;
  xb[(size_t)(o0 + 0) * NN] = f2bf(a0.x);  xb[(size_t)(o0 + 1) * NN] = f2bf(a0.y);
  xb[(size_t)(o0 + 2) * NN] = f2bf(a0.z);  xb[(size_t)(o0 + 3) * NN] = f2bf(a0.w);
  xb[(size_t)(o0 + 4) * NN] = f2bf(a1.x);  xb[(size_t)(o0 + 5) * NN] = f2bf(a1.y);
  xb[(size_t)(o0 + 6) * NN] = f2bf(a1.z);  xb[(size_t)(o0 + 7) * NN] = f2bf(a1.w);
  xb[(size_t)(o0 + 8) * NN] = f2bf(a2.x);  xb[(size_t)(o0 + 9) * NN] = f2bf(a2.y);
  xb[(size_t)(o0 +10) * NN] = f2bf(a2.z);  xb[(size_t)(o0 +11) * NN] = f2bf(a2.w);
  xb[(size_t)(o0 +12) * NN] = f2bf(a3.x);  xb[(size_t)(o0 +13) * NN] = f2bf(a3.y);
  xb[(size_t)(o0 +14) * NN] = f2bf(a3.z);  xb[(size_t)(o0 +15) * NN] = f2bf(a3.w);
}

// K2b: thr[n] = 0.1*(1e-9 + csd[n]) analytic
__global__ __launch_bounds__(256) void k2b_thr(
    const float* __restrict__ xyz4, const float* __restrict__ sums,
    float* __restrict__ thr) {
  const int idx = blockIdx.x * 256 + threadIdx.x;
  const int b = idx >> 12;
  const float4 pn = *(const float4*)(xyz4 + (size_t)idx * 4);
  const float Px = sums[b * 4 + 0], Py = sums[b * 4 + 1];
  const float Pz = sums[b * 4 + 2], S1 = sums[b * 4 + 3];
  float csd = fmaf((float)NN, pn.w, S1)
            - 2.f * (pn.x * Px + pn.y * Py + pn.z * Pz);
  thr[idx] = POS_COEF * (1e-9f + csd);
}

// ===================== fallback (round-13) p1/p3/k7 =====================

__global__ __launch_bounds__(256) void p1_rs1(
    const float* __restrict__ qt, const float* __restrict__ qk,
    float* __restrict__ irs1) {
  const int tid = threadIdx.x;
  const int b = blockIdx.x >> 8;
  const int m0 = (blockIdx.x & 255) << 4;
  const int w = tid >> 6, lane = tid & 63;
  const float* qb = qt + (size_t)b * NN * 16;
  const float* kb = qk + (size_t)b * 16 * NN;
  const int mA = m0 + w, mB = m0 + w + 4, mC = m0 + w + 8, mD = m0 + w + 12;
  LQROW(ma, qb + (size_t)mA * 16)
  LQROW(mb, qb + (size_t)mB * 16)
  LQROW(mc, qb + (size_t)mC * 16)
  LQROW(md, qb + (size_t)mD * 16)
  float sA = 0.f, sB = 0.f, sC = 0.f, sD = 0.f;
  for (int it = 0; it < 16; ++it) {
    const int n0 = (it << 8) + (lane << 2);
    LKPL(kb, n0)
    sA += __expf(fminf(DOTC(ma0,ma1,ma2,ma3,x), 80.f));
    sA += __expf(fminf(DOTC(ma0,ma1,ma2,ma3,y), 80.f));
    sA += __expf(fminf(DOTC(ma0,ma1,ma2,ma3,z), 80.f));
    sA += __expf(fminf(DOTC(ma0,ma1,ma2,ma3,w), 80.f));
    sB += __expf(fminf(DOTC(mb0,mb1,mb2,mb3,x), 80.f));
    sB += __expf(fminf(DOTC(mb0,mb1,mb2,mb3,y), 80.f));
    sB += __expf(fminf(DOTC(mb0,mb1,mb2,mb3,z), 80.f));
    sB += __expf(fminf(DOTC(mb0,mb1,mb2,mb3,w), 80.f));
    sC += __expf(fminf(DOTC(mc0,mc1,mc2,mc3,x), 80.f));
    sC += __expf(fminf(DOTC(mc0,mc1,mc2,mc3,y), 80.f));
    sC += __expf(fminf(DOTC(mc0,mc1,mc2,mc3,z), 80.f));
    sC += __expf(fminf(DOTC(mc0,mc1,mc2,mc3,w), 80.f));
    sD += __expf(fminf(DOTC(md0,md1,md2,md3,x), 80.f));
    sD += __expf(fminf(DOTC(md0,md1,md2,md3,y), 80.f));
    sD += __expf(fminf(DOTC(md0,md1,md2,md3,z), 80.f));
    sD += __expf(fminf(DOTC(md0,md1,md2,md3,w), 80.f));
  }
  WRED(sA) WRED(sB) WRED(sC) WRED(sD)
  if (lane == 0) {
    irs1[b * NN + mA] = rcpf_(sA);
    irs1[b * NN + mB] = rcpf_(sB);
    irs1[b * NN + mC] = rcpf_(sC);
    irs1[b * NN + mD] = rcpf_(sD);
  }
}

__global__ __launch_bounds__(256) void p3_rs2(
    const float* __restrict__ qt, const float* __restrict__ qk,
    const float* __restrict__ xyz4, const float* __restrict__ xyzk,
    const float* __restrict__ irs1, const float* __restrict__ ics1,
    const float* __restrict__ thr, float* __restrict__ irs2) {
  const int tid = threadIdx.x;
  const int b = blockIdx.x >> 8;
  const int m0 = (blockIdx.x & 255) << 4;
  const int w = tid >> 6, lane = tid & 63;
  const float* qb = qt + (size_t)b * NN * 16;
  const float* kb = qk + (size_t)b * 16 * NN;
  const float* xk = xyzk + (size_t)b * 4 * NN;
  const int mA = m0 + w, mB = m0 + w + 4, mC = m0 + w + 8, mD = m0 + w + 12;
  LQROW(ma, qb + (size_t)mA * 16)
  LQROW(mb, qb + (size_t)mB * 16)
  LQROW(mc, qb + (size_t)mC * 16)
  LQROW(md, qb + (size_t)mD * 16)
  const float4 pmA = *(const float4*)(xyz4 + ((size_t)b * NN + mA) * 4);
  const float4 pmB = *(const float4*)(xyz4 + ((size_t)b * NN + mB) * 4);
  const float4 pmC = *(const float4*)(xyz4 + ((size_t)b * NN + mC) * 4);
  const float4 pmD = *(const float4*)(xyz4 + ((size_t)b * NN + mD) * 4);
  const float rA = irs1[b * NN + mA];
  const float rB = irs1[b * NN + mB];
  const float rC = irs1[b * NN + mC];
  const float rD = irs1[b * NN + mD];
  float sA = 0.f, sB = 0.f, sC = 0.f, sD = 0.f;
#define P3C(S, M0,M1,M2,M3, PM, R, C) { \
    float corr_ = DOTC(M0,M1,M2,M3,C); \
    float a1v_ = __expf(fminf(corr_, 80.f)) * (R) * ic.C; \
    float dd_ = (PM).w + pw.C - 2.f * ((PM).x * px.C + (PM).y * py.C + (PM).z * pz.C); \
    dd_ = fmaxf(dd_, 0.f); \
    float l0_ = (dd_ <= th.C) ? a1v_ : 0.f; \
    S += __expf(l0_); }
  for (int it = 0; it < 16; ++it) {
    const int n0 = (it << 8) + (lane << 2);
    LKPL(kb, n0)
    const float4 px = *(const float4*)(xk + 0*NN + n0);
    const float4 py = *(const float4*)(xk + 1*NN + n0);
    const float4 pz = *(const float4*)(xk + 2*NN + n0);
    const float4 pw = *(const float4*)(xk + 3*NN + n0);
    const float4 ic = *(const float4*)(ics1 + b * NN + n0);
    const float4 th = *(const float4*)(thr + b * NN + n0);
    P3C(sA, ma0,ma1,ma2,ma3, pmA, rA, x)
    P3C(sA, ma0,ma1,ma2,ma3, pmA, rA, y)
    P3C(sA, ma0,ma1,ma2,ma3, pmA, rA, z)
    P3C(sA, ma0,ma1,ma2,ma3, pmA, rA, w)
    P3C(sB, mb0,mb1,mb2,mb3, pmB, rB, x)
    P3C(sB, mb0,mb1,mb2,mb3, pmB, rB, y)
    P3C(sB, mb0,mb1,mb2,mb3, pmB, rB, z)
    P3C(sB, mb0,mb1,mb2,mb3, pmB, rB, w)
    P3C(sC, mc0,mc1,mc2,mc3, pmC, rC, x)
    P3C(sC, mc0,mc1,mc2,mc3, pmC, rC, y)
    P3C(sC, mc0,mc1,mc2,mc3, pmC, rC, z)
    P3C(sC, mc0,mc1,mc2,mc3, pmC, rC, w)
    P3C(sD, md0,md1,md2,md3, pmD, rD, x)
    P3C(sD, md0,md1,md2,md3, pmD, rD, y)
    P3C(sD, md0,md1,md2,md3, pmD, rD, z)
    P3C(sD, md0,md1,md2,md3, pmD, rD, w)
  }
#undef P3C
  WRED(sA) WRED(sB) WRED(sC) WRED(sD)
  if (lane == 0) {
    irs2[b * NN + mA] = rcpf_(sA);
    irs2[b * NN + mB] = rcpf_(sB);
    irs2[b * NN + mC] = rcpf_(sC);
    irs2[b * NN + mD] = rcpf_(sD);
  }
}

__global__ __launch_bounds__(256) void k7_gma(
    const float* __restrict__ qt, const float* __restrict__ xyz4,
    const unsigned short* __restrict__ xvb,
    const float* __restrict__ irs1, const float* __restrict__ irs2,
    const float* __restrict__ ics1, const float* __restrict__ thr,
    float* __restrict__ g1, float* __restrict__ g2, float* __restrict__ cs2) {
  const int tid = threadIdx.x;
  const int bid = blockIdx.x;
  const int msl = bid & 7;
  const int nb = (bid >> 3) & 63;
  const int b = bid >> 9;
  const int n0 = nb << 6;
  const int mstart = msl << 9;
  __shared__ __align__(16) unsigned short attns1[64 * 72];
  __shared__ __align__(16) unsigned short attns2[64 * 72];
  __shared__ __align__(16) unsigned short xvs[64 * 72];
  const float* qb = qt + (size_t)b * NN * 16;
  const float* pb = xyz4 + (size_t)b * NN * 4;
  const int ni = tid & 63, aw = tid >> 6;
  const int na = n0 + ni;
  const float* qnp = qb + (size_t)na * 16;
  LQROW(q, qnp)
  const float4 pn = *(const float4*)(pb + (size_t)na * 4);
  const float ics1n = ics1[b * NN + na];
  const float thr_n = thr[b * NN + na];
  const int lane = tid & 63, wv = tid >> 6;
  const int lr = lane & 15, quad = lane >> 4;
  const int nw = wv << 4;
  f32x4v acc0 = {0,0,0,0}, acc1 = {0,0,0,0}, acc2 = {0,0,0,0}, acc3 = {0,0,0,0};
  f32x4v d0 = {0,0,0,0}, d1 = {0,0,0,0}, d2 = {0,0,0,0}, d3 = {0,0,0,0};
  float csacc = 0.f;
#define COMPA(MOFF, D1, D2) { \
    const int m_ = __builtin_amdgcn_readfirstlane(mw + (MOFF)); \
    const float* qm_ = qb + (size_t)m_ * 16; \
    LQROW(wq, qm_) \
    float corr_ = DOT16M(q0, q1, q2, q3, wq0, wq1, wq2, wq3); \
    const float4 pm_ = *(const float4*)(pb + (size_t)m_ * 4); \
    float a1v_ = __expf(fminf(corr_, 80.f)) * irs1[b * NN + m_] * ics1n; \
    float dd_ = pm_.w + pn.w - 2.f * (pm_.x * pn.x + pm_.y * pn.y + pm_.z * pn.z); \
    dd_ = fmaxf(dd_, 0.f); \
    float l0_ = (dd_ <= thr_n) ? a1v_ : 0.f; \
    float l2n_ = __expf(l0_) * irs2[b * NN + m_]; \
    D1 = f2bf(a1v_); D2 = f2bf(l2n_); csacc += l2n_; }
  for (int mt = 0; mt < 8; ++mt) {
    const int m0 = mstart + (mt << 6);
    __syncthreads();
    {
      const int c = tid >> 2, part = tid & 3;
      const unsigned short* src = xvb + ((size_t)b * 64 + c) * NN + m0 + part * 16;
      unsigned short* dst = xvs + c * 72 + part * 16;
      *(uint4*)dst = *(const uint4*)src;
      *(uint4*)(dst + 8) = *(const uint4*)(src + 8);
    }
    const int mw = m0 + (aw << 4);
#pragma unroll
    for (int g = 0; g < 4; ++g) {
      ushort4 u1, u2;
      COMPA(g * 4 + 0, u1.x, u2.x)
      COMPA(g * 4 + 1, u1.y, u2.y)
      COMPA(g * 4 + 2, u1.z, u2.z)
      COMPA(g * 4 + 3, u1.w, u2.w)
      *(ushort4*)(attns1 + ni * 72 + (aw << 4) + (g << 2)) = u1;
      *(ushort4*)(attns2 + ni * 72 + (aw << 4) + (g << 2)) = u2;
    }
    __syncthreads();
#pragma unroll
    for (int h = 0; h < 2; ++h) {
      const bf16x8 a1 = *(const bf16x8*)(attns1 + (nw + lr) * 72 + h * 32 + quad * 8);
      const bf16x8 a2 = *(const bf16x8*)(attns2 + (nw + lr) * 72 + h * 32 + quad * 8);
      const bf16x8 b0 = *(const bf16x8*)(xvs + (lr) * 72 + h * 32 + quad * 8);
      const bf16x8 b1 = *(const bf16x8*)(xvs + (16 + lr) * 72 + h * 32 + quad * 8);
      const bf16x8 b2 = *(const bf16x8*)(xvs + (32 + lr) * 72 + h * 32 + quad * 8);
      const bf16x8 b3 = *(const bf16x8*)(xvs + (48 + lr) * 72 + h * 32 + quad * 8);
      acc0 = __builtin_amdgcn_mfma_f32_16x16x32_bf16(a1, b0, acc0, 0, 0, 0);
      acc1 = __builtin_amdgcn_mfma_f32_16x16x32_bf16(a1, b1, acc1, 0, 0, 0);
      acc2 = __builtin_amdgcn_mfma_f32_16x16x32_bf16(a1, b2, acc2, 0, 0, 0);
      acc3 = __builtin_amdgcn_mfma_f32_16x16x32_bf16(a1, b3, acc3, 0, 0, 0);
      d0 = __builtin_amdgcn_mfma_f32_16x16x32_bf16(a2, b0, d0, 0, 0, 0);
      d1 = __builtin_amdgcn_mfma_f32_16x16x32_bf16(a2, b1, d1, 0, 0, 0);
      d2 = __builtin_amdgcn_mfma_f32_16x16x32_bf16(a2, b2, d2, 0, 0, 0);
      d3 = __builtin_amdgcn_mfma_f32_16x16x32_bf16(a2, b3, d3, 0, 0, 0);
    }
  }
#undef COMPA
  atomicAdd(&cs2[b * NN + na], csacc);
#define EPI(ACC, DST, CT) { \
    float* g_ = (DST) + ((size_t)b * NN + n0 + nw + (quad << 2)) * 64 + (CT) * 16 + lr; \
    atomicAdd(g_ + 0,   ACC[0]); \
    atomicAdd(g_ + 64,  ACC[1]); \
    atomicAdd(g_ + 128, ACC[2]); \
    atomicAdd(g_ + 192, ACC[3]); }
  EPI(acc0, g1, 0) EPI(acc1, g1, 1) EPI(acc2, g1, 2) EPI(acc3, g1, 3)
  EPI(d0, g2, 0) EPI(d1, g2, 1) EPI(d2, g2, 2) EPI(d3, g2, 3)
#undef EPI
}

// ============ materialized-exp path (used iff ws_size permits) ============

// P1W: like p1 but stores a0[m][n]=bf16(exp(corr)) and sums the ROUNDED values.
__global__ __launch_bounds__(256) void p1w_rs1(
    const float* __restrict__ qt, const float* __restrict__ qk,
    float* __restrict__ irs1, unsigned short* __restrict__ a0g) {
  const int tid = threadIdx.x;
  const int b = blockIdx.x >> 8;
  const int m0 = (blockIdx.x & 255) << 4;
  const int w = tid >> 6, lane = tid & 63;
  const float* qb = qt + (size_t)b * NN * 16;
  const float* kb = qk + (size_t)b * 16 * NN;
  unsigned short* ab = a0g + (size_t)b * NN * NN;
  const int mA = m0 + w, mB = m0 + w + 4, mC = m0 + w + 8, mD = m0 + w + 12;
  LQROW(ma, qb + (size_t)mA * 16)
  LQROW(mb, qb + (size_t)mB * 16)
  LQROW(mc, qb + (size_t)mC * 16)
  LQROW(md, qb + (size_t)mD * 16)
  float sA = 0.f, sB = 0.f, sC = 0.f, sD = 0.f;
#define P1E(S, U, UC, M0,M1,M2,M3, C) { \
    float e_ = __expf(fminf(DOTC(M0,M1,M2,M3,C), 80.f)); \
    unsigned short us_ = f2bf(e_); U.UC = us_; S += bf2f(us_); }
  for (int it = 0; it < 16; ++it) {
    const int n0 = (it << 8) + (lane << 2);
    LKPL(kb, n0)
    ushort4 uA, uB, uC, uD;
    P1E(sA, uA, x, ma0,ma1,ma2,ma3, x) P1E(sA, uA, y, ma0,ma1,ma2,ma3, y)
    P1E(sA, uA, z, ma0,ma1,ma2,ma3, z) P1E(sA, uA, w, ma0,ma1,ma2,ma3, w)
    P1E(sB, uB, x, mb0,mb1,mb2,mb3, x) P1E(sB, uB, y, mb0,mb1,mb2,mb3, y)
    P1E(sB, uB, z, mb0,mb1,mb2,mb3, z) P1E(sB, uB, w, mb0,mb1,mb2,mb3, w)
    P1E(sC, uC, x, mc0,mc1,mc2,mc3, x) P1E(sC, uC, y, mc0,mc1,mc2,mc3, y)
    P1E(sC, uC, z, mc0,mc1,mc2,mc3, z) P1E(sC, uC, w, mc0,mc1,mc2,mc3, w)
    P1E(sD, uD, x, md0,md1,md2,md3, x) P1E(sD, uD, y, md0,md1,md2,md3, y)
    P1E(sD, uD, z, md0,md1,md2,md3, z) P1E(sD, uD, w, md0,md1,md2,md3, w)
    *(ushort4*)(ab + (size_t)mA * NN + n0) = uA;
    *(ushort4*)(ab + (size_t)mB * NN + n0) = uB;
    *(ushort4*)(ab + (size_t)mC * NN + n0) = uC;
    *(ushort4*)(ab + (size_t)mD * NN + n0) = uD;
  }
#undef P1E
  WRED(sA) WRED(sB) WRED(sC) WRED(sD)
  if (lane == 0) {
    irs1[b * NN + mA] = rcpf_(sA);
    irs1[b * NN + mB] = rcpf_(sB);
    irs1[b * NN + mC] = rcpf_(sC);
    irs1[b * NN + mD] = rcpf_(sD);
  }
}

// P3W: reads a0 rows (no corr recompute), stores ae[m][n]=bf16(exp(l0)),
// sums ROUNDED values for irs2.
__global__ __launch_bounds__(256) void p3w_rs2(
    const float* __restrict__ xyz4, const float* __restrict__ xyzk,
    const float* __restrict__ irs1, const float* __restrict__ ics1,
    const float* __restrict__ thr, float* __restrict__ irs2,
    const unsigned short* __restrict__ a0g, unsigned short* __restrict__ aeg) {
  const int tid = threadIdx.x;
  const int b = blockIdx.x >> 8;
  const int m0 = (blockIdx.x & 255) << 4;
  const int w = tid >> 6, lane = tid & 63;
  const float* xk = xyzk + (size_t)b * 4 * NN;
  const unsigned short* ab = a0g + (size_t)b * NN * NN;
  unsigned short* eb = aeg + (size_t)b * NN * NN;
  const int mA = m0 + w, mB = m0 + w + 4, mC = m0 + w + 8, mD = m0 + w + 12;
  const float4 pmA = *(const float4*)(xyz4 + ((size_t)b * NN + mA) * 4);
  const float4 pmB = *(const float4*)(xyz4 + ((size_t)b * NN + mB) * 4);
  const float4 pmC = *(const float4*)(xyz4 + ((size_t)b * NN + mC) * 4);
  const float4 pmD = *(const float4*)(xyz4 + ((size_t)b * NN + mD) * 4);
  const float rA = irs1[b * NN + mA];
  const float rB = irs1[b * NN + mB];
  const float rC = irs1[b * NN + mC];
  const float rD = irs1[b * NN + mD];
  float sA = 0.f, sB = 0.f, sC = 0.f, sD = 0.f;
#define P3W(S, RU, EU, UC, PM, R, C) { \
    float a1v_ = bf2f(RU.UC) * (R) * ic.C; \
    float dd_ = (PM).w + pw.C - 2.f * ((PM).x * px.C + (PM).y * py.C + (PM).z * pz.C); \
    dd_ = fmaxf(dd_, 0.f); \
    float l0_ = (dd_ <= th.C) ? a1v_ : 0.f; \
    unsigned short us_ = f2bf(__expf(l0_)); EU.UC = us_; S += bf2f(us_); }
  for (int it = 0; it < 16; ++it) {
    const int n0 = (it << 8) + (lane << 2);
    const float4 px = *(const float4*)(xk + 0*NN + n0);
    const float4 py = *(const float4*)(xk + 1*NN + n0);
    const float4 pz = *(const float4*)(xk + 2*NN + n0);
    const float4 pw = *(const float4*)(xk + 3*NN + n0);
    const float4 ic = *(const float4*)(ics1 + b * NN + n0);
    const float4 th = *(const float4*)(thr + b * NN + n0);
    const ushort4 rA4 = *(const ushort4*)(ab + (size_t)mA * NN + n0);
    const ushort4 rB4 = *(const ushort4*)(ab + (size_t)mB * NN + n0);
    const ushort4 rC4 = *(const ushort4*)(ab + (size_t)mC * NN + n0);
    const ushort4 rD4 = *(const ushort4*)(ab + (size_t)mD * NN + n0);
    ushort4 eA, eB, eC, eD;
    P3W(sA, rA4, eA, x, pmA, rA, x) P3W(sA, rA4, eA, y, pmA, rA, y)
    P3W(sA, rA4, eA, z, pmA, rA, z) P3W(sA, rA4, eA, w, pmA, rA, w)
    P3W(sB, rB4, eB, x, pmB, rB, x) P3W(sB, rB4, eB, y, pmB, rB, y)
    P3W(sB, rB4, eB, z, pmB, rB, z) P3W(sB, rB4, eB, w, pmB, rB, w)
    P3W(sC, rC4, eC, x, pmC, rC, x) P3W(sC, rC4, eC, y, pmC, rC, y)
    P3W(sC, rC4, eC, z, pmC, rC, z) P3W(sC, rC4, eC, w, pmC, rC, w)
    P3W(sD, rD4, eD, x, pmD, rD, x) P3W(sD, rD4, eD, y, pmD, rD, y)
    P3W(sD, rD4, eD, z, pmD, rD, z) P3W(sD, rD4, eD, w, pmD, rD, w)
    *(ushort4*)(eb + (size_t)mA * NN + n0) = eA;
    *(ushort4*)(eb + (size_t)mB * NN + n0) = eB;
    *(ushort4*)(eb + (size_t)mC * NN + n0) = eC;
    *(ushort4*)(eb + (size_t)mD * NN + n0) = eD;
  }
#undef P3W
  WRED(sA) WRED(sB) WRED(sC) WRED(sD)
  if (lane == 0) {
    irs2[b * NN + mA] = rcpf_(sA);
    irs2[b * NN + mB] = rcpf_(sB);
    irs2[b * NN + mC] = rcpf_(sC);
    irs2[b * NN + mD] = rcpf_(sD);
  }
}

// K7F: phase A reads materialized exp rows (2 loads + 2 muls/element).
__global__ __launch_bounds__(256) void k7f_gma(
    const unsigned short* __restrict__ a0g, const unsigned short* __restrict__ aeg,
    const unsigned short* __restrict__ xvb,
    const float* __restrict__ irs1, const float* __restrict__ irs2,
    const float* __restrict__ ics1,
    float* __restrict__ g1, float* __restrict__ g2, float* __restrict__ cs2) {
  const int tid = threadIdx.x;
  const int bid = blockIdx.x;
  const int msl = bid & 7;
  const int nb = (bid >> 3) & 63;
  const int b = bid >> 9;
  const int n0 = nb << 6;
  const int mstart = msl << 9;
  __shared__ __align__(16) unsigned short attns1[64 * 72];
  __shared__ __align__(16) unsigned short attns2[64 * 72];
  __shared__ __align__(16) unsigned short xvs[64 * 72];
  const unsigned short* ab = a0g + (size_t)b * NN * NN;
  const unsigned short* eb = aeg + (size_t)b * NN * NN;
  const int ni = tid & 63, aw = tid >> 6;
  const int na = n0 + ni;
  const float ics1n = ics1[b * NN + na];
  const int lane = tid & 63, wv = tid >> 6;
  const int lr = lane & 15, quad = lane >> 4;
  const int nw = wv << 4;
  f32x4v acc0 = {0,0,0,0}, acc1 = {0,0,0,0}, acc2 = {0,0,0,0}, acc3 = {0,0,0,0};
  f32x4v d0 = {0,0,0,0}, d1 = {0,0,0,0}, d2 = {0,0,0,0}, d3 = {0,0,0,0};
  float csacc = 0.f;
#define COMPF(MOFF, D1, D2) { \
    const int m_ = __builtin_amdgcn_readfirstlane(mw + (MOFF)); \
    float raw0_ = bf2f(ab[(size_t)m_ * NN + na]); \
    float rawe_ = bf2f(eb[(size_t)m_ * NN + na]); \
    float a1v_ = raw0_ * irs1[b * NN + m_] * ics1n; \
    float l2n_ = rawe_ * irs2[b * NN + m_]; \
    D1 = f2bf(a1v_); D2 = f2bf(l2n_); csacc += l2n_; }
  for (int mt = 0; mt < 8; ++mt) {
    const int m0 = mstart + (mt << 6);
    __syncthreads();
    {
      const int c = tid >> 2, part = tid & 3;
      const unsigned short* src = xvb + ((size_t)b * 64 + c) * NN + m0 + part * 16;
      unsigned short* dst = xvs + c * 72 + part * 16;
      *(uint4*)dst = *(const uint4*)src;
      *(uint4*)(dst + 8) = *(const uint4*)(src + 8);
    }
    const int mw = m0 + (aw << 4);
#pragma unroll
    for (int g = 0; g < 4; ++g) {
      ushort4 u1, u2;
      COMPF(g * 4 + 0, u1.x, u2.x)
      COMPF(g * 4 + 1, u1.y, u2.y)
      COMPF(g * 4 + 2, u1.z, u2.z)
      COMPF(g * 4 + 3, u1.w, u2.w)
      *(ushort4*)(attns1 + ni * 72 + (aw << 4) + (g << 2)) = u1;
      *(ushort4*)(attns2 + ni * 72 + (aw << 4) + (g << 2)) = u2;
    }
    __syncthreads();
#pragma unroll
    for (int h = 0; h < 2; ++h) {
      const bf16x8 a1 = *(const bf16x8*)(attns1 + (nw + lr) * 72 + h * 32 + quad * 8);
      const bf16x8 a2 = *(const bf16x8*)(attns2 + (nw + lr) * 72 + h * 32 + quad * 8);
      const bf16x8 b0 = *(const bf16x8*)(xvs + (lr) * 72 + h * 32 + quad * 8);
      const bf16x8 b1 = *(const bf16x8*)(xvs + (16 + lr) * 72 + h * 32 + quad * 8);
      const bf16x8 b2 = *(const bf16x8*)(xvs + (32 + lr) * 72 + h * 32 + quad * 8);
      const bf16x8 b3 = *(const bf16x8*)(xvs + (48 + lr) * 72 + h * 32 + quad * 8);
      acc0 = __builtin_amdgcn_mfma_f32_16x16x32_bf16(a1, b0, acc0, 0, 0, 0);
      acc1 = __builtin_amdgcn_mfma_f32_16x16x32_bf16(a1, b1, acc1, 0, 0, 0);
      acc2 = __builtin_amdgcn_mfma_f32_16x16x32_bf16(a1, b2, acc2, 0, 0, 0);
      acc3 = __builtin_amdgcn_mfma_f32_16x16x32_bf16(a1, b3, acc3, 0, 0, 0);
      d0 = __builtin_amdgcn_mfma_f32_16x16x32_bf16(a2, b0, d0, 0, 0, 0);
      d1 = __builtin_amdgcn_mfma_f32_16x16x32_bf16(a2, b1, d1, 0, 0, 0);
      d2 = __builtin_amdgcn_mfma_f32_16x16x32_bf16(a2, b2, d2, 0, 0, 0);
      d3 = __builtin_amdgcn_mfma_f32_16x16x32_bf16(a2, b3, d3, 0, 0, 0);
    }
  }
#undef COMPF
  atomicAdd(&cs2[b * NN + na], csacc);
#define EPI(ACC, DST, CT) { \
    float* g_ = (DST) + ((size_t)b * NN + n0 + nw + (quad << 2)) * 64 + (CT) * 16 + lr; \
    atomicAdd(g_ + 0,   ACC[0]); \
    atomicAdd(g_ + 64,  ACC[1]); \
    atomicAdd(g_ + 128, ACC[2]); \
    atomicAdd(g_ + 192, ACC[3]); }
  EPI(acc0, g1, 0) EPI(acc1, g1, 1) EPI(acc2, g1, 2) EPI(acc3, g1, 3)
  EPI(d0, g2, 0) EPI(d1, g2, 1) EPI(d2, g2, 2) EPI(d3, g2, 3)
#undef EPI
}

// ===================== common p2 / k8 / k9 =====================

__global__ __launch_bounds__(256) void p2_cs1(
    const float* __restrict__ qt, const float* __restrict__ qk,
    const float* __restrict__ irs1, float* __restrict__ ics1) {
  const int tid = threadIdx.x;
  const int b = blockIdx.x >> 8;
  const int n0t = (blockIdx.x & 255) << 4;
  const int w = tid >> 6, lane = tid & 63;
  const float* qb = qt + (size_t)b * NN * 16;
  const float* kb = qk + (size_t)b * 16 * NN;
  const int nA = n0t + w, nB = n0t + w + 4, nC = n0t + w + 8, nD = n0t + w + 12;
  LQROW(na, qb + (size_t)nA * 16)
  LQROW(nb, qb + (size_t)nB * 16)
  LQROW(nc, qb + (size_t)nC * 16)
  LQROW(nd, qb + (size_t)nD * 16)
  float sA = 0.f, sB = 0.f, sC = 0.f, sD = 0.f;
  for (int it = 0; it < 16; ++it) {
    const int m0 = (it << 8) + (lane << 2);
    LKPL(kb, m0)
    const float4 r1 = *(const float4*)(irs1 + b * NN + m0);
    sA = fmaf(__expf(fminf(DOTC(na0,na1,na2,na3,x), 80.f)), r1.x, sA);
    sA = fmaf(__expf(fminf(DOTC(na0,na1,na2,na3,y), 80.f)), r1.y, sA);
    sA = fmaf(__expf(fminf(DOTC(na0,na1,na2,na3,z), 80.f)), r1.z, sA);
    sA = fmaf(__expf(fminf(DOTC(na0,na1,na2,na3,w), 80.f)), r1.w, sA);
    sB = fmaf(__expf(fminf(DOTC(nb0,nb1,nb2,nb3,x), 80.f)), r1.x, sB);
    sB = fmaf(__expf(fminf(DOTC(nb0,nb1,nb2,nb3,y), 80.f)), r1.y, sB);
    sB = fmaf(__expf(fminf(DOTC(nb0,nb1,nb2,nb3,z), 80.f)), r1.z, sB);
    sB = fmaf(__expf(fminf(DOTC(nb0,nb1,nb2,nb3,w), 80.f)), r1.w, sB);
    sC = fmaf(__expf(fminf(DOTC(nc0,nc1,nc2,nc3,x), 80.f)), r1.x, sC);
    sC = fmaf(__expf(fminf(DOTC(nc0,nc1,nc2,nc3,y), 80.f)), r1.y, sC);
    sC = fmaf(__expf(fminf(DOTC(nc0,nc1,nc2,nc3,z), 80.f)), r1.z, sC);
    sC = fmaf(__expf(fminf(DOTC(nc0,nc1,nc2,nc3,w), 80.f)), r1.w, sC);
    sD = fmaf(__expf(fminf(DOTC(nd0,nd1,nd2,nd3,x), 80.f)), r1.x, sD);
    sD = fmaf(__expf(fminf(DOTC(nd0,nd1,nd2,nd3,y), 80.f)), r1.y, sD);
    sD = fmaf(__expf(fminf(DOTC(nd0,nd1,nd2,nd3,z), 80.f)), r1.z, sD);
    sD = fmaf(__expf(fminf(DOTC(nd0,nd1,nd2,nd3,w), 80.f)), r1.w, sD);
  }
  WRED(sA) WRED(sB) WRED(sC) WRED(sD)
  if (lane == 0) {
    ics1[b * NN + nA] = rcpf_(1e-9f + sA);
    ics1[b * NN + nB] = rcpf_(1e-9f + sB);
    ics1[b * NN + nC] = rcpf_(1e-9f + sC);
    ics1[b * NN + nD] = rcpf_(1e-9f + sD);
  }
}

__global__ __launch_bounds__(256) void k8_res(
    const void* __restrict__ mot, const void* __restrict__ wt,
    const void* __restrict__ bt, const float* __restrict__ flag,
    float* __restrict__ g1_res, const float* __restrict__ g2,
    const float* __restrict__ cs2, float* __restrict__ gn) {
  const bool f32 = flag[0] > 0.5f;
  const int tid = threadIdx.x;
  const int bid = blockIdx.x;
  const int b = bid >> 9;
  const int n0 = (bid & 511) << 3;
  __shared__ float wtT[64 * 65];
  __shared__ float bts[64];
  __shared__ float md[8 * 64];
  __shared__ float gs[8], gss[8];
  for (int i = tid; i < 4096; i += 256) {
    int o = i & 63, c = i >> 6;
    wtT[c * 65 + o] = ldin(wt, o * 64 + c, f32);
  }
  if (tid < 64) bts[tid] = ldin(bt, tid, f32);
  if (tid < 8) { gs[tid] = 0.f; gss[tid] = 0.f; }
#pragma unroll
  for (int r = 0; r < 2; ++r) {
    const int idx = tid * 2 + r;
    const int c = idx & 63, nl = idx >> 6;
    const size_t gi = ((size_t)b * NN + n0 + nl) * 64 + c;
    const float ics2n = rcpf_(1e-9f + cs2[b * NN + n0 + nl]);
    float gmav = fmaf(g2[gi], ics2n, g1_res[gi]);
    md[nl * 64 + c] = ldin(mot, ((size_t)b * 64 + c) * NN + n0 + nl, f32) - gmav;
  }
  __syncthreads();
  const int o = tid & 63, ng = tid >> 6;
  const int nl0 = ng * 2, nl1 = ng * 2 + 1;
  float a0 = bts[o], a1 = bts[o];
#pragma unroll 8
  for (int c = 0; c < 64; ++c) {
    float w = wtT[c * 65 + o];
    a0 = fmaf(w, md[nl0 * 64 + c], a0);
    a1 = fmaf(w, md[nl1 * 64 + c], a1);
  }
  g1_res[((size_t)b * NN + n0 + nl0) * 64 + o] = a0;
  g1_res[((size_t)b * NN + n0 + nl1) * 64 + o] = a1;
  atomicAdd(&gs[o >> 3], a0 + a1);
  atomicAdd(&gss[o >> 3], a0 * a0 + a1 * a1);
  __syncthreads();
  if (tid < 8) atomicAdd(&gn[b * 8 + tid], gs[tid]);
  else if (tid < 16) atomicAdd(&gn[16 + b * 8 + (tid - 8)], gss[tid - 8]);
}

__global__ __launch_bounds__(256) void k9_out(
    const float* __restrict__ res, const float* __restrict__ gn,
    const void* __restrict__ mot,
    const void* __restrict__ gnw, const void* __restrict__ gnb,
    const void* __restrict__ pa, const void* __restrict__ al,
    const float* __restrict__ flag, void* __restrict__ out) {
  const bool f32 = flag[0] > 0.5f;
  const int idx = blockIdx.x * 256 + threadIdx.x;
  const int n = idx & 4095;
  const int c = (idx >> 12) & 63;
  const int b = idx >> 18;
  const int g = c >> 3;
  const float inv_cnt = 1.f / 32768.f;
  float mean = gn[b * 8 + g] * inv_cnt;
  float var = gn[16 + b * 8 + g] * inv_cnt - mean * mean;
  var = fmaxf(var, 0.f);
  float rstd = rsqrtf(var + 1e-5f);
  float r = res[((size_t)b * NN + n) * 64 + c];
  float y = (r - mean) * rstd * ldin(gnw, c, f32) + ldin(gnb, c, f32);
  float slope = ldin(pa, 0, f32);
  y = (y >= 0.f) ? y : slope * y;
  float o = ldin(al, 0, f32) * y + ldin(mot, idx, f32);
  if (f32) ((float*)out)[idx] = o;
  else     ((__hip_bfloat16*)out)[idx] = __float2bfloat16(o);
}

extern "C" void kernel_launch(void* const* d_in, const int* in_sizes, int n_in,
                              void* d_out, int out_size, void* d_ws, size_t ws_size,
                              hipStream_t stream) {
  const void* ctx = d_in[0];
  const void* mot = d_in[1];
  const void* xyz = d_in[2];
  const void* wqk = d_in[3];
  const void* wv  = d_in[4];
  const void* bv  = d_in[5];
  const void* wt  = d_in[6];
  const void* bt  = d_in[7];
  const void* gnw = d_in[8];
  const void* gnb = d_in[9];
  const void* pa  = d_in[10];
  const void* al  = d_in[11];
  float* ws = (float*)d_ws;
  const bool big = ws_size >= (size_t)FULL_F * sizeof(float);

  if (ws_size < (size_t)WS_TOTAL * sizeof(float))
    fprintf(stderr, "[gma3d] WARNING ws_size=%zu < needed %zu\n",
            ws_size, (size_t)WS_TOTAL * sizeof(float));

  hipMemsetAsync(ws + OFF_SUMS, 0, (size_t)ZERO_F * sizeof(float), stream);

  k0_detect<<<1, 256, 0, stream>>>((const unsigned short*)ctx, ws + OFF_FLAG);
  k1_q_xyz<<<32, 256, 0, stream>>>(ctx, xyz, wqk, ws + OFF_FLAG,
                                   ws + OFF_QT, ws + OFF_QK,
                                   ws + OFF_XYZ4, ws + OFF_XYZK, ws + OFF_SUMS);
  k2_xv<<<128, 256, 0, stream>>>(mot, wv, bv, ws + OFF_FLAG,
                                 (unsigned short*)(ws + OFF_XVB));
  k2b_thr<<<32, 256, 0, stream>>>(ws + OFF_XYZ4, ws + OFF_SUMS, ws + OFF_THR);

  if (big) {
    unsigned short* a0 = (unsigned short*)(ws + OFF_A0);
    unsigned short* ae = (unsigned short*)(ws + OFF_AE);
    p1w_rs1<<<512, 256, 0, stream>>>(ws + OFF_QT, ws + OFF_QK, ws + OFF_IRS1, a0);
    p2_cs1<<<512, 256, 0, stream>>>(ws + OFF_QT, ws + OFF_QK, ws + OFF_IRS1, ws + OFF_ICS1);
    p3w_rs2<<<512, 256, 0, stream>>>(ws + OFF_XYZ4, ws + OFF_XYZK,
                                     ws + OFF_IRS1, ws + OFF_ICS1, ws + OFF_THR,
                                     ws + OFF_IRS2, a0, ae);
    k7f_gma<<<1024, 256, 0, stream>>>(a0, ae,
                                      (const unsigned short*)(ws + OFF_XVB),
                                      ws + OFF_IRS1, ws + OFF_IRS2, ws + OFF_ICS1,
                                      ws + OFF_GMA, ws + OFF_G2, ws + OFF_CS2);
  } else {
    p1_rs1<<<512, 256, 0, stream>>>(ws + OFF_QT, ws + OFF_QK, ws + OFF_IRS1);
    p2_cs1<<<512, 256, 0, stream>>>(ws + OFF_QT, ws + OFF_QK, ws + OFF_IRS1, ws + OFF_ICS1);
    p3_rs2<<<512, 256, 0, stream>>>(ws + OFF_QT, ws + OFF_QK,
                                    ws + OFF_XYZ4, ws + OFF_XYZK,
                                    ws + OFF_IRS1, ws + OFF_ICS1, ws + OFF_THR,
                                    ws + OFF_IRS2);
    k7_gma<<<1024, 256, 0, stream>>>(ws + OFF_QT, ws + OFF_XYZ4,
                                     (const unsigned short*)(ws + OFF_XVB),
                                     ws + OFF_IRS1, ws + OFF_IRS2,
                                     ws + OFF_ICS1, ws + OFF_THR,
                                     ws + OFF_GMA, ws + OFF_G2, ws + OFF_CS2);
  }

  k8_res<<<1024, 256, 0, stream>>>(mot, wt, bt, ws + OFF_FLAG,
                                   ws + OFF_GMA, ws + OFF_G2, ws + OFF_CS2, ws + OFF_GN);
  k9_out<<<2048, 256, 0, stream>>>(ws + OFF_GMA, ws + OFF_GN, mot, gnw, gnb, pa, al,
                                   ws + OFF_FLAG, d_out);
}